// Round 5
// baseline (169.410 us; speedup 1.0000x reference)
//
#include <hip/hip_runtime.h>

#define NNODE 16384
#define DD 32
#define INPC 256
#define UC 128
#define RC 8
#define EC 8

typedef __attribute__((ext_vector_type(8))) short short8;
typedef __attribute__((ext_vector_type(4))) float float4v;
typedef __attribute__((ext_vector_type(4))) unsigned uint4v;

__device__ __forceinline__ unsigned short f2bf(float f) {
    unsigned u = __builtin_bit_cast(unsigned, f);
    unsigned r = (u + 0x7FFFu + ((u >> 16) & 1u)) >> 16;   // RNE
    return (unsigned short)r;
}
__device__ __forceinline__ float bf2f(unsigned short s) { return __builtin_bit_cast(float, (unsigned)s << 16); }

// load 8 consecutive fp32 and convert to a bf16 MFMA fragment half
__device__ __forceinline__ short8 ld8bf(const float* p) {
    float4 v0 = *(const float4*)p;
    float4 v1 = *(const float4*)(p + 4);
    short8 a;
    a[0] = (short)f2bf(v0.x); a[1] = (short)f2bf(v0.y);
    a[2] = (short)f2bf(v0.z); a[3] = (short)f2bf(v0.w);
    a[4] = (short)f2bf(v1.x); a[5] = (short)f2bf(v1.y);
    a[6] = (short)f2bf(v1.z); a[7] = (short)f2bf(v1.w);
    return a;
}

// B-fragment flat index for mfma_f32_16x16x32_bf16. nct = #16-col tiles.
__device__ __forceinline__ int bfrag_idx(int k, int col, int nct) {
    int ks = k >> 5, ct = col >> 4;
    int l = (((k >> 3) & 3) << 4) | (col & 15);
    return (((ks * nct + ct) << 6) + l) * 8 + (k & 7);
}

// ---------- setup: [0,1024) pew->frag | [1024,1088) prep (MFMA) | [1088,1152) hist ----------
__global__ void k_setup(const float* __restrict__ pew, const float* __restrict__ qw,
                        const float* __restrict__ kw, const float* __restrict__ relw,
                        const float* __restrict__ vw, const float* __restrict__ fcw,
                        const int* __restrict__ pe,
                        unsigned short* __restrict__ pewfrag,
                        unsigned short* __restrict__ BallQfrag, unsigned short* __restrict__ RVFfrag,
                        int* __restrict__ blockhist) {
    __shared__ unsigned short stage_s[128 * 132];   // ~33.8 KB: vw then fcw (bf16)
    __shared__ unsigned short mat_s[16 * 136];      // ~4.35 KB: P then RV (bf16)
    __shared__ int hh[8];
    int b = blockIdx.x;
    if (b < 1024) {                   // pew -> B-fragments (K=256, N=128 per entity)
        int id = b * 256 + threadIdx.x;
        int e = id >> 15, k = (id >> 7) & 255, col = id & 127;
        pewfrag[(e << 15) + bfrag_idx(k, col, 8)] = f2bf(pew[id]);
        return;
    }
    if (b < 1088) {                   // prep: all four small GEMMs via MFMA
        int pb = b - 1024;
        int r = pb & 7, i0 = (pb >> 3) * 16;
        int w = threadIdx.x >> 6, l = threadIdx.x & 63;
        int mrow = l & 15, kgrp = (l >> 4) << 3;
        const float* R = relw + r * (UC * UC);

        // ---- phase P: P rows i0..i0+16 = qw[i0..] @ kw^T
        float4v accP[2] = {};
        #pragma unroll
        for (int ks = 0; ks < 4; ++ks) {
            short8 a = ld8bf(&qw[(i0 + mrow) * UC + ks * 32 + kgrp]);
            #pragma unroll
            for (int ci = 0; ci < 2; ++ci) {
                int ct = w * 2 + ci;
                short8 bf = ld8bf(&kw[(ct * 16 + mrow) * UC + ks * 32 + kgrp]);
                accP[ci] = __builtin_amdgcn_mfma_f32_16x16x32_bf16(a, bf, accP[ci], 0, 0, 0);
            }
        }
        #pragma unroll
        for (int ci = 0; ci < 2; ++ci)
            #pragma unroll
            for (int reg = 0; reg < 4; ++reg) {
                int row = ((l >> 4) << 2) + reg;
                int col = (w * 2 + ci) * 16 + mrow;
                mat_s[row * 136 + col] = f2bf(accP[ci][reg] * (1.0f / 128.0f));
            }
        // stage vw (bf16, stride 132)
        for (int it = 0; it < 16; ++it) {
            int idx = it * 256 + threadIdx.x;      // float4 index
            int row = idx >> 5, col = (idx & 31) * 4;
            float4 v = *(const float4*)&vw[row * UC + col];
            uint2 o;
            o.x = (unsigned)f2bf(v.x) | ((unsigned)f2bf(v.y) << 16);
            o.y = (unsigned)f2bf(v.z) | ((unsigned)f2bf(v.w) << 16);
            *(uint2*)&stage_s[row * 132 + col] = o;
        }
        __syncthreads();

        // ---- phase M: M = P @ R^T ; phase RV: RV = R @ vw (interleaved)
        float4v accM[2] = {}, accV[2] = {};
        #pragma unroll
        for (int ks = 0; ks < 4; ++ks) {
            short8 aM = *(const short8*)&mat_s[mrow * 136 + ks * 32 + kgrp];
            short8 aV = ld8bf(&R[(i0 + mrow) * UC + ks * 32 + kgrp]);
            #pragma unroll
            for (int ci = 0; ci < 2; ++ci) {
                int ct = w * 2 + ci;
                short8 bM = ld8bf(&R[(ct * 16 + mrow) * UC + ks * 32 + kgrp]);
                accM[ci] = __builtin_amdgcn_mfma_f32_16x16x32_bf16(aM, bM, accM[ci], 0, 0, 0);
                uint4v pv;
                #pragma unroll
                for (int jp = 0; jp < 4; ++jp) {
                    unsigned e0 = stage_s[(ks * 32 + kgrp + jp * 2) * 132 + ct * 16 + mrow];
                    unsigned e1 = stage_s[(ks * 32 + kgrp + jp * 2 + 1) * 132 + ct * 16 + mrow];
                    pv[jp] = e0 | (e1 << 16);
                }
                accV[ci] = __builtin_amdgcn_mfma_f32_16x16x32_bf16(
                    aV, __builtin_bit_cast(short8, pv), accV[ci], 0, 0, 0);
            }
        }
        #pragma unroll
        for (int ci = 0; ci < 2; ++ci)
            #pragma unroll
            for (int reg = 0; reg < 4; ++reg) {
                int i = i0 + ((l >> 4) << 2) + reg;
                int col = r * 128 + (w * 2 + ci) * 16 + mrow;
                BallQfrag[bfrag_idx(i, col, 64)] = f2bf(accM[ci][reg]);
            }
        __syncthreads();   // mat_s / stage_s reads done
        // store RV rows; stage fcw
        #pragma unroll
        for (int ci = 0; ci < 2; ++ci)
            #pragma unroll
            for (int reg = 0; reg < 4; ++reg)
                mat_s[(((l >> 4) << 2) + reg) * 136 + (w * 2 + ci) * 16 + mrow] = f2bf(accV[ci][reg]);
        for (int it = 0; it < 16; ++it) {
            int idx = it * 256 + threadIdx.x;
            int row = idx >> 5, col = (idx & 31) * 4;
            float4 v = *(const float4*)&fcw[row * UC + col];
            uint2 o;
            o.x = (unsigned)f2bf(v.x) | ((unsigned)f2bf(v.y) << 16);
            o.y = (unsigned)f2bf(v.z) | ((unsigned)f2bf(v.w) << 16);
            *(uint2*)&stage_s[row * 132 + col] = o;
        }
        __syncthreads();

        // ---- phase RVF: RVF = RV @ fcw
        float4v accF[2] = {};
        #pragma unroll
        for (int ks = 0; ks < 4; ++ks) {
            short8 aF = *(const short8*)&mat_s[mrow * 136 + ks * 32 + kgrp];
            #pragma unroll
            for (int ci = 0; ci < 2; ++ci) {
                int ct = w * 2 + ci;
                uint4v pv;
                #pragma unroll
                for (int jp = 0; jp < 4; ++jp) {
                    unsigned e0 = stage_s[(ks * 32 + kgrp + jp * 2) * 132 + ct * 16 + mrow];
                    unsigned e1 = stage_s[(ks * 32 + kgrp + jp * 2 + 1) * 132 + ct * 16 + mrow];
                    pv[jp] = e0 | (e1 << 16);
                }
                accF[ci] = __builtin_amdgcn_mfma_f32_16x16x32_bf16(
                    aF, __builtin_bit_cast(short8, pv), accF[ci], 0, 0, 0);
            }
        }
        #pragma unroll
        for (int ci = 0; ci < 2; ++ci)
            #pragma unroll
            for (int reg = 0; reg < 4; ++reg) {
                int i = i0 + ((l >> 4) << 2) + reg;
                int col = (w * 2 + ci) * 16 + mrow;
                RVFfrag[bfrag_idx(r * 128 + i, col, 8)] = f2bf(accF[ci][reg]);
            }
        return;
    }
    {   // hist
        int hb = b - 1088;
        if (threadIdx.x < 8) hh[threadIdx.x] = 0;
        __syncthreads();
        atomicAdd(&hh[pe[hb * 256 + threadIdx.x]], 1);
        __syncthreads();
        if (threadIdx.x < 8) blockhist[hb * 8 + threadIdx.x] = hh[threadIdx.x];
    }
}

// ---------- scatter: wave-parallel scan + ballot rank (no global atomics) ----------
__global__ void k_scatter(const int* __restrict__ pe, const int* __restrict__ blockhist,
                          int* __restrict__ list, int* __restrict__ cnt, int* __restrict__ basep) {
    __shared__ int boff[8];
    __shared__ int totS[8], exS[8];
    __shared__ int wavecnt[4 * 8];
    int t = threadIdx.x, w = t >> 6, l = t & 63;
    if (w == 0) {
        #pragma unroll
        for (int e = 0; e < 8; ++e) {
            int h = blockhist[l * 8 + e];
            int pref = h;
            #pragma unroll
            for (int off = 1; off < 64; off <<= 1) {
                int v = __shfl_up(pref, off, 64);
                pref += (l >= off) ? v : 0;
            }
            if (l == (int)blockIdx.x) exS[e] = pref - h;
            if (l == 63) totS[e] = pref;
        }
    }
    __syncthreads();
    if (t == 0) {
        int run = 0;
        #pragma unroll
        for (int e = 0; e < 8; ++e) {
            boff[e] = run + exS[e];
            if (blockIdx.x == 0) { basep[e] = run; cnt[e] = totS[e]; }
            run += totS[e];
        }
    }
    __syncthreads();
    int n = blockIdx.x * 256 + t;
    int e = pe[n];
    unsigned long long mymask = 0;
    #pragma unroll
    for (int r = 0; r < 8; ++r) {
        unsigned long long m = __ballot(e == r);
        if (e == r) mymask = m;
        if (l == r) wavecnt[w * 8 + r] = (int)__popcll(m);
    }
    __syncthreads();
    int off = 0;
    for (int w2 = 0; w2 < w; ++w2) off += wavecnt[w2 * 8 + e];
    unsigned long long ltmask = (1ull << l) - 1ull;
    int rank = (int)__popcll(mymask & ltmask);
    list[boff[e] + off + rank] = n;
}

// ---------- center (MFMA): reads fp32 ns directly, converts in-register ----------
__global__ __launch_bounds__(256, 4)
void k_center(const float* __restrict__ ns, const unsigned short* __restrict__ pewfrag,
              const int* __restrict__ list, const int* __restrict__ cnt,
              const int* __restrict__ base, unsigned short* __restrict__ center_bf) {
    int e = blockIdx.y;
    int c = cnt[e];
    int start = blockIdx.x * 16;
    if (start >= c) return;
    int w = threadIdx.x >> 6, l = threadIdx.x & 63;

    int rid = list[base[e] + min(start + (l & 15), c - 1)];

    float4v acc[2] = {};
    const unsigned short* pf = pewfrag + ((size_t)e << 15);
    #pragma unroll
    for (int ks = 0; ks < 8; ++ks) {
        short8 a = ld8bf(&ns[(size_t)rid * 256 + ks * 32 + ((l >> 4) << 3)]);
        #pragma unroll
        for (int ci = 0; ci < 2; ++ci) {
            int ct = w * 2 + ci;
            short8 b = *(const short8*)&pf[(((ks * 8 + ct) << 6) + l) * 8];
            acc[ci] = __builtin_amdgcn_mfma_f32_16x16x32_bf16(a, b, acc[ci], 0, 0, 0);
        }
    }
    #pragma unroll
    for (int reg = 0; reg < 4; ++reg) {
        int row16 = start + ((l >> 4) << 2) + reg;
        if (row16 < c) {
            int gid = list[base[e] + row16];
            #pragma unroll
            for (int ci = 0; ci < 2; ++ci)
                center_bf[(size_t)gid * 128 + (w * 2 + ci) * 16 + (l & 15)] = f2bf(acc[ci][reg]);
        }
    }
}

// ---------- final: transposed-scores phase B ----------
// scores^T = mfma(A = qr-rows (qlds), B = X (xp regs)) -> S[rel][edge] with
// edge = lane&15, which the lane already owns (rv/ai resident). Selection is
// 3 cndmask + 1 shfl per t; softmax is 2 exp + 8 shfl_xor; A-frag build is
// 8 shfls from a pre-selected md register (no edata array).
// xs (bucket staging, per wave 32edges x 128ch bf16, 8KB): u16 addr =
//   edge*128 + (ch ^ (((edge>>3)&3)<<4))
// Write: lane owns edge t*16+(l&15), chunks ch0=ks*32+(l>>4)*8 (16B, swz-safe
// since swz only touches bits>=4). Read (fixed jj): edge=(l>>4)*8+jj ->
// swz=(l>>4)<<4 varies per group -> 64 lanes cover 64 distinct u16 slots
// = 2 lanes/bank (free, m136).
#define QSTRIDE 1096
__global__ __launch_bounds__(256, 2)
void k_final(const unsigned short* __restrict__ center_bf,
             const unsigned short* __restrict__ BallQfrag,
             const unsigned short* __restrict__ RVFfrag,
             const int* __restrict__ adj, const int* __restrict__ rel,
             const float* __restrict__ fcb, float* __restrict__ out) {
    __shared__ unsigned short qlds[16 * QSTRIDE];            // ~35 KB
    __shared__ __align__(16) unsigned short xs[4][4096];     // 32 KB: per-wave X staging
    int w = threadIdx.x >> 6, l = threadIdx.x & 63;
    int n0 = blockIdx.x * 16;

    // ---- preload adjacency/relations for this wave's 4 nodes (index dep only on l&15)
    int aiq[4][2], rvq[4][2], rvrow[4][2];
    #pragma unroll
    for (int q = 0; q < 4; ++q) {
        int n = n0 + w * 4 + q;
        #pragma unroll
        for (int t = 0; t < 2; ++t) {
            aiq[q][t] = adj[n * DD + t * 16 + (l & 15)];
            rvq[q][t] = rel[n * DD + t * 16 + (l & 15)];
            rvrow[q][t] = aiq[q][t] > 0 ? aiq[q][t] - 1 : 0;
        }
    }

    // X prefetch for q=0 (lands under phase A): xp[t][ks] = X[edge t*16+(l&15)][ks*32+(l>>4)*8..+8]
    short8 xp[2][4];
    #pragma unroll
    for (int t = 0; t < 2; ++t)
        #pragma unroll
        for (int ks = 0; ks < 4; ++ks)
            xp[t][ks] = *(const short8*)&center_bf[(size_t)rvrow[0][t] * 128 + ks * 32 + ((l >> 4) << 3)];

    // phase A: qr tile (16 nodes x 1024) into LDS; wave w computes cols w*256..+256
    {
        short8 a[4];
        #pragma unroll
        for (int ks = 0; ks < 4; ++ks)
            a[ks] = *(const short8*)&center_bf[(size_t)(n0 + (l & 15)) * 128 + ks * 32 + ((l >> 4) << 3)];
        for (int ci = 0; ci < 16; ++ci) {
            int ct = w * 16 + ci;
            float4v acc = {};
            #pragma unroll
            for (int ks = 0; ks < 4; ++ks) {
                short8 b = *(const short8*)&BallQfrag[(((ks * 64 + ct) << 6) + l) * 8];
                acc = __builtin_amdgcn_mfma_f32_16x16x32_bf16(a[ks], b, acc, 0, 0, 0);
            }
            int r = ct >> 3;
            int ch = (ct & 7) * 16 + (l & 15);
            #pragma unroll
            for (int reg = 0; reg < 4; ++reg) {
                int rn = ((l >> 4) << 2) + reg;
                qlds[rn * QSTRIDE + r * 136 + ch] = f2bf(acc[reg]);
            }
        }
    }
    __syncthreads();

    unsigned short* xsw = &xs[w][0];

    // phase B: wave w handles nodes n0 + w*4 .. +4
    #pragma unroll
    for (int q = 0; q < 4; ++q) {
        int tn = w * 4 + q;
        int ai0 = aiq[q][0], ai1 = aiq[q][1];
        int rv0 = rvq[q][0], rv1 = rvq[q][1];

        // 1. write xs from xp (bucket staging for THIS q; xp prefetched last iter)
        #pragma unroll
        for (int t = 0; t < 2; ++t) {
            int edge = t * 16 + (l & 15);
            unsigned swz = (((unsigned)edge >> 3) & 3u) << 4;
            #pragma unroll
            for (int ks = 0; ks < 4; ++ks) {
                unsigned ch0 = (unsigned)(ks * 32 + ((l >> 4) << 3));
                *(short8*)&xsw[(unsigned)(edge * 128) + (ch0 ^ swz)] = xp[t][ks];
            }
        }

        // 2. scores^T: S[rel(m, dup x2)][edge n=l&15] = mfma(A=qb, B=xp)
        //    A[m=l&15][k=(l>>4)*8+j] = qr[tn][rel=(l&7)][ch]  (same read as before)
        //    B[k][n=l&15] = X[edge t*16+n][ch]                (xp verbatim)
        float4v sc[2] = {};
        #pragma unroll
        for (int ks = 0; ks < 4; ++ks) {
            short8 qb = *(const short8*)&qlds[tn * QSTRIDE + (l & 7) * 136 + ks * 32 + ((l >> 4) << 3)];
            sc[0] = __builtin_amdgcn_mfma_f32_16x16x32_bf16(qb, xp[0][ks], sc[0], 0, 0, 0);
            sc[1] = __builtin_amdgcn_mfma_f32_16x16x32_bf16(qb, xp[1][ks], sc[1], 0, 0, 0);
        }

        // 3. prefetch next q's X (overwrites xp after last use; hides under softmax+bucket)
        if (q < 3) {
            #pragma unroll
            for (int t = 0; t < 2; ++t)
                #pragma unroll
                for (int ks = 0; ks < 4; ++ks)
                    xp[t][ks] = *(const short8*)&center_bf[(size_t)rvrow[q + 1][t] * 128
                                                           + ks * 32 + ((l >> 4) << 3)];
        }

        // 4. select S[rv][own edge]: lane's regs hold rows m=(l>>4)*4+reg (rel = m&7,
        //    rows 8..15 duplicate 0..7). Needed row rv lives in group rv>>2 at reg rv&3;
        //    source lane shares l&15 -> same rv -> in-lane reg-select then one shfl.
        float sel0, sel1;
        {
            int r = rv0;
            float v01 = (r & 1) ? sc[0][1] : sc[0][0];
            float v23 = (r & 1) ? sc[0][3] : sc[0][2];
            float regv = (r & 2) ? v23 : v01;
            float s = __shfl(regv, ((r >> 2) << 4) | (l & 15), 64);
            if (ai0 == 0) s = 0.f;
            if (r == 0) s = -1e9f;
            sel0 = s;
        }
        {
            int r = rv1;
            float v01 = (r & 1) ? sc[1][1] : sc[1][0];
            float v23 = (r & 1) ? sc[1][3] : sc[1][2];
            float regv = (r & 2) ? v23 : v01;
            float s = __shfl(regv, ((r >> 2) << 4) | (l & 15), 64);
            if (ai1 == 0) s = 0.f;
            if (r == 0) s = -1e9f;
            sel1 = s;
        }

        // 5. softmax over 32 edges = {t} x {16 lanes}; groups replicate identically
        float mx = fmaxf(sel0, sel1);
        mx = fmaxf(mx, __shfl_xor(mx, 1, 64));
        mx = fmaxf(mx, __shfl_xor(mx, 2, 64));
        mx = fmaxf(mx, __shfl_xor(mx, 4, 64));
        mx = fmaxf(mx, __shfl_xor(mx, 8, 64));
        float at0 = __expf(sel0 - mx);
        float at1 = __expf(sel1 - mx);
        float sm = at0 + at1;
        sm += __shfl_xor(sm, 1, 64);
        sm += __shfl_xor(sm, 2, 64);
        sm += __shfl_xor(sm, 4, 64);
        sm += __shfl_xor(sm, 8, 64);
        float inv = 1.0f / sm;
        at0 *= inv; at1 *= inv;
        if (ai0 == 0) at0 = 0.f;          // pad rows contribute 0
        if (ai1 == 0) at1 = 0.f;

        // 6. bucket A-frag via shfl: dest lane wants edge E=(l>>4)*8+jj held by
        //    source S=(l&48)|(((l>>4)&1)*8+jj); S pre-selects md by its own t=(group>>1),
        //    which equals the asker's E>>4 (same group).
        unsigned md0 = (unsigned)f2bf(at0) | ((unsigned)rv0 << 16);
        unsigned md1 = (unsigned)f2bf(at1) | ((unsigned)rv1 << 16);
        unsigned mdsel = (l >= 32) ? md1 : md0;
        unsigned aw[4];
        #pragma unroll
        for (int jp = 0; jp < 4; ++jp) {
            unsigned m0 = __shfl(mdsel, (l & 48) | (((l >> 4) & 1) * 8 + jp * 2), 64);
            unsigned m1 = __shfl(mdsel, (l & 48) | (((l >> 4) & 1) * 8 + jp * 2 + 1), 64);
            unsigned s0 = ((m0 >> 16) == (unsigned)(l & 15)) ? (m0 & 0xFFFFu) : 0u;
            unsigned s1 = ((m1 >> 16) == (unsigned)(l & 15)) ? (m1 & 0xFFFFu) : 0u;
            aw[jp] = s0 | (s1 << 16);
        }
        uint4v av = {aw[0], aw[1], aw[2], aw[3]};
        short8 afrag = __builtin_bit_cast(short8, av);

        // 7. bucket via MFMA: B-frag k=(l>>4)*8+jj (edge), n=l&15 (ch within ct tile)
        #pragma unroll
        for (int ct = 0; ct < 8; ++ct) {
            unsigned short p[8];
            #pragma unroll
            for (int jj = 0; jj < 8; ++jj) {
                int edge = (l >> 4) * 8 + jj;
                unsigned addr = (unsigned)(edge * 128)
                              + (((unsigned)(ct * 16 + (l & 15))) ^ ((((unsigned)edge >> 3) & 3u) << 4));
                p[jj] = xsw[addr];
            }
            uint4v bv = {(unsigned)p[0] | ((unsigned)p[1] << 16),
                         (unsigned)p[2] | ((unsigned)p[3] << 16),
                         (unsigned)p[4] | ((unsigned)p[5] << 16),
                         (unsigned)p[6] | ((unsigned)p[7] << 16)};
            float4v zc = {};
            float4v acc = __builtin_amdgcn_mfma_f32_16x16x32_bf16(
                afrag, __builtin_bit_cast(short8, bv), zc, 0, 0, 0);
            if (l < 32) {     // C rows 0..7 = relations; rows 8..15 are zero
                int rbase = (l >> 4) << 2;
                #pragma unroll
                for (int reg = 0; reg < 4; ++reg)
                    qlds[tn * QSTRIDE + (rbase + reg) * 136 + ct * 16 + (l & 15)] = f2bf(acc[reg]);
            }
        }
    }
    __syncthreads();

    // phase C: agg16x128 = bucket(16x1024, r-stride 136) @ RVF(1024x128), fused epilogue
    // A-operand hoisted: one ds_read per ks feeds both ci accumulators.
    {
        float4v acc[2] = {};
        #pragma unroll 4
        for (int ks = 0; ks < 32; ++ks) {
            short8 a = *(const short8*)&qlds[(l & 15) * QSTRIDE + (ks >> 2) * 136
                                             + (ks & 3) * 32 + ((l >> 4) << 3)];
            #pragma unroll
            for (int ci = 0; ci < 2; ++ci) {
                int ct = w * 2 + ci;
                short8 b = *(const short8*)&RVFfrag[(((ks * 8 + ct) << 6) + l) * 8];
                acc[ci] = __builtin_amdgcn_mfma_f32_16x16x32_bf16(a, b, acc[ci], 0, 0, 0);
            }
        }
        #pragma unroll
        for (int ci = 0; ci < 2; ++ci) {
            int ct = w * 2 + ci;
            int col = ct * 16 + (l & 15);
            float bb = fcb[col];
            #pragma unroll
            for (int reg = 0; reg < 4; ++reg) {
                int n = n0 + ((l >> 4) << 2) + reg;
                float v = acc[ci][reg] + bb;
                v = v > 0.f ? v : 0.f;
                out[(size_t)n * 128 + col] = bf2f(center_bf[(size_t)n * 128 + col]) + v;
            }
        }
    }
}

extern "C" void kernel_launch(void* const* d_in, const int* in_sizes, int n_in,
                              void* d_out, int out_size, void* d_ws, size_t ws_size,
                              hipStream_t stream) {
    const float* node_state = (const float*)d_in[0];
    const int*   adjacency  = (const int*)d_in[1];
    const int*   point_enc  = (const int*)d_in[2];
    const int*   relation   = (const int*)d_in[3];
    const float* pew        = (const float*)d_in[4];
    const float* relw       = (const float*)d_in[5];
    const float* qw         = (const float*)d_in[6];
    const float* kw         = (const float*)d_in[7];
    const float* vw         = (const float*)d_in[8];
    const float* fcw        = (const float*)d_in[9];
    const float* fcb        = (const float*)d_in[10];
    float* out = (float*)d_out;

    char* ws = (char*)d_ws;
    unsigned short* BallQfrag = (unsigned short*)ws;  ws += 128 * 1024 * 2;            // 256 KB
    unsigned short* RVFfrag   = (unsigned short*)ws;  ws += 1024 * 128 * 2;            // 256 KB
    unsigned short* center_bf = (unsigned short*)ws;  ws += (size_t)NNODE * 128 * 2;   // 4 MB
    unsigned short* pewfrag   = (unsigned short*)ws;  ws += 8 * 32768 * 2;             // 512 KB
    int* blockhist            = (int*)ws;             ws += 64 * 8 * 4;
    int* cnt                  = (int*)ws;             ws += 32;
    int* basep                = (int*)ws;             ws += 32;
    int* list                 = (int*)ws;             ws += NNODE * 4;                 // 64 KB

    k_setup<<<1152, 256, 0, stream>>>(pew, qw, kw, relw, vw, fcw, point_enc,
                                      pewfrag, BallQfrag, RVFfrag, blockhist);
    k_scatter<<<64, 256, 0, stream>>>(point_enc, blockhist, list, cnt, basep);
    k_center<<<dim3(192, 8), 256, 0, stream>>>(node_state, pewfrag, list, cnt, basep, center_bf);
    k_final<<<NNODE / 16, 256, 0, stream>>>(center_bf, BallQfrag, RVFfrag,
                                            adjacency, relation, fcb, out);
}

// Round 6
// 165.254 us; speedup vs baseline: 1.0251x; 1.0251x over previous
//
#include <hip/hip_runtime.h>

#define NNODE 16384
#define DD 32
#define INPC 256
#define UC 128
#define RC 8
#define EC 8

typedef __attribute__((ext_vector_type(8))) short short8;
typedef __attribute__((ext_vector_type(4))) float float4v;
typedef __attribute__((ext_vector_type(4))) unsigned uint4v;

__device__ __forceinline__ unsigned short f2bf(float f) {
    unsigned u = __builtin_bit_cast(unsigned, f);
    unsigned r = (u + 0x7FFFu + ((u >> 16) & 1u)) >> 16;   // RNE
    return (unsigned short)r;
}
__device__ __forceinline__ float bf2f(unsigned short s) { return __builtin_bit_cast(float, (unsigned)s << 16); }

// load 8 consecutive fp32 and convert to a bf16 MFMA fragment half
__device__ __forceinline__ short8 ld8bf(const float* p) {
    float4 v0 = *(const float4*)p;
    float4 v1 = *(const float4*)(p + 4);
    short8 a;
    a[0] = (short)f2bf(v0.x); a[1] = (short)f2bf(v0.y);
    a[2] = (short)f2bf(v0.z); a[3] = (short)f2bf(v0.w);
    a[4] = (short)f2bf(v1.x); a[5] = (short)f2bf(v1.y);
    a[6] = (short)f2bf(v1.z); a[7] = (short)f2bf(v1.w);
    return a;
}

// B-fragment flat index for mfma_f32_16x16x32_bf16. nct = #16-col tiles.
__device__ __forceinline__ int bfrag_idx(int k, int col, int nct) {
    int ks = k >> 5, ct = col >> 4;
    int l = (((k >> 3) & 3) << 4) | (col & 15);
    return (((ks * nct + ct) << 6) + l) * 8 + (k & 7);
}

// ---------- setup: [0,1024) pew->frag | [1024,1088) prep (MFMA) | [1088,1152) hist ----------
__global__ void k_setup(const float* __restrict__ pew, const float* __restrict__ qw,
                        const float* __restrict__ kw, const float* __restrict__ relw,
                        const float* __restrict__ vw, const float* __restrict__ fcw,
                        const int* __restrict__ pe,
                        unsigned short* __restrict__ pewfrag,
                        unsigned short* __restrict__ BallQfrag, unsigned short* __restrict__ RVFfrag,
                        int* __restrict__ blockhist) {
    __shared__ unsigned short stage_s[128 * 132];   // ~33.8 KB: vw then fcw (bf16)
    __shared__ unsigned short mat_s[16 * 136];      // ~4.35 KB: P then RV (bf16)
    __shared__ int hh[8];
    int b = blockIdx.x;
    if (b < 1024) {                   // pew -> B-fragments (K=256, N=128 per entity)
        int id = b * 256 + threadIdx.x;
        int e = id >> 15, k = (id >> 7) & 255, col = id & 127;
        pewfrag[(e << 15) + bfrag_idx(k, col, 8)] = f2bf(pew[id]);
        return;
    }
    if (b < 1088) {                   // prep: all four small GEMMs via MFMA
        int pb = b - 1024;
        int r = pb & 7, i0 = (pb >> 3) * 16;
        int w = threadIdx.x >> 6, l = threadIdx.x & 63;
        int mrow = l & 15, kgrp = (l >> 4) << 3;
        const float* R = relw + r * (UC * UC);

        // ---- phase P: P rows i0..i0+16 = qw[i0..] @ kw^T
        float4v accP[2] = {};
        #pragma unroll
        for (int ks = 0; ks < 4; ++ks) {
            short8 a = ld8bf(&qw[(i0 + mrow) * UC + ks * 32 + kgrp]);
            #pragma unroll
            for (int ci = 0; ci < 2; ++ci) {
                int ct = w * 2 + ci;
                short8 bf = ld8bf(&kw[(ct * 16 + mrow) * UC + ks * 32 + kgrp]);
                accP[ci] = __builtin_amdgcn_mfma_f32_16x16x32_bf16(a, bf, accP[ci], 0, 0, 0);
            }
        }
        #pragma unroll
        for (int ci = 0; ci < 2; ++ci)
            #pragma unroll
            for (int reg = 0; reg < 4; ++reg) {
                int row = ((l >> 4) << 2) + reg;
                int col = (w * 2 + ci) * 16 + mrow;
                mat_s[row * 136 + col] = f2bf(accP[ci][reg] * (1.0f / 128.0f));
            }
        // stage vw (bf16, stride 132)
        for (int it = 0; it < 16; ++it) {
            int idx = it * 256 + threadIdx.x;      // float4 index
            int row = idx >> 5, col = (idx & 31) * 4;
            float4 v = *(const float4*)&vw[row * UC + col];
            uint2 o;
            o.x = (unsigned)f2bf(v.x) | ((unsigned)f2bf(v.y) << 16);
            o.y = (unsigned)f2bf(v.z) | ((unsigned)f2bf(v.w) << 16);
            *(uint2*)&stage_s[row * 132 + col] = o;
        }
        __syncthreads();

        // ---- phase M: M = P @ R^T ; phase RV: RV = R @ vw (interleaved)
        float4v accM[2] = {}, accV[2] = {};
        #pragma unroll
        for (int ks = 0; ks < 4; ++ks) {
            short8 aM = *(const short8*)&mat_s[mrow * 136 + ks * 32 + kgrp];
            short8 aV = ld8bf(&R[(i0 + mrow) * UC + ks * 32 + kgrp]);
            #pragma unroll
            for (int ci = 0; ci < 2; ++ci) {
                int ct = w * 2 + ci;
                short8 bM = ld8bf(&R[(ct * 16 + mrow) * UC + ks * 32 + kgrp]);
                accM[ci] = __builtin_amdgcn_mfma_f32_16x16x32_bf16(aM, bM, accM[ci], 0, 0, 0);
                uint4v pv;
                #pragma unroll
                for (int jp = 0; jp < 4; ++jp) {
                    unsigned e0 = stage_s[(ks * 32 + kgrp + jp * 2) * 132 + ct * 16 + mrow];
                    unsigned e1 = stage_s[(ks * 32 + kgrp + jp * 2 + 1) * 132 + ct * 16 + mrow];
                    pv[jp] = e0 | (e1 << 16);
                }
                accV[ci] = __builtin_amdgcn_mfma_f32_16x16x32_bf16(
                    aV, __builtin_bit_cast(short8, pv), accV[ci], 0, 0, 0);
            }
        }
        #pragma unroll
        for (int ci = 0; ci < 2; ++ci)
            #pragma unroll
            for (int reg = 0; reg < 4; ++reg) {
                int i = i0 + ((l >> 4) << 2) + reg;
                int col = r * 128 + (w * 2 + ci) * 16 + mrow;
                BallQfrag[bfrag_idx(i, col, 64)] = f2bf(accM[ci][reg]);
            }
        __syncthreads();   // mat_s / stage_s reads done
        // store RV rows; stage fcw
        #pragma unroll
        for (int ci = 0; ci < 2; ++ci)
            #pragma unroll
            for (int reg = 0; reg < 4; ++reg)
                mat_s[(((l >> 4) << 2) + reg) * 136 + (w * 2 + ci) * 16 + mrow] = f2bf(accV[ci][reg]);
        for (int it = 0; it < 16; ++it) {
            int idx = it * 256 + threadIdx.x;
            int row = idx >> 5, col = (idx & 31) * 4;
            float4 v = *(const float4*)&fcw[row * UC + col];
            uint2 o;
            o.x = (unsigned)f2bf(v.x) | ((unsigned)f2bf(v.y) << 16);
            o.y = (unsigned)f2bf(v.z) | ((unsigned)f2bf(v.w) << 16);
            *(uint2*)&stage_s[row * 132 + col] = o;
        }
        __syncthreads();

        // ---- phase RVF: RVF = RV @ fcw
        float4v accF[2] = {};
        #pragma unroll
        for (int ks = 0; ks < 4; ++ks) {
            short8 aF = *(const short8*)&mat_s[mrow * 136 + ks * 32 + kgrp];
            #pragma unroll
            for (int ci = 0; ci < 2; ++ci) {
                int ct = w * 2 + ci;
                uint4v pv;
                #pragma unroll
                for (int jp = 0; jp < 4; ++jp) {
                    unsigned e0 = stage_s[(ks * 32 + kgrp + jp * 2) * 132 + ct * 16 + mrow];
                    unsigned e1 = stage_s[(ks * 32 + kgrp + jp * 2 + 1) * 132 + ct * 16 + mrow];
                    pv[jp] = e0 | (e1 << 16);
                }
                accF[ci] = __builtin_amdgcn_mfma_f32_16x16x32_bf16(
                    aF, __builtin_bit_cast(short8, pv), accF[ci], 0, 0, 0);
            }
        }
        #pragma unroll
        for (int ci = 0; ci < 2; ++ci)
            #pragma unroll
            for (int reg = 0; reg < 4; ++reg) {
                int i = i0 + ((l >> 4) << 2) + reg;
                int col = (w * 2 + ci) * 16 + mrow;
                RVFfrag[bfrag_idx(r * 128 + i, col, 8)] = f2bf(accF[ci][reg]);
            }
        return;
    }
    {   // hist
        int hb = b - 1088;
        if (threadIdx.x < 8) hh[threadIdx.x] = 0;
        __syncthreads();
        atomicAdd(&hh[pe[hb * 256 + threadIdx.x]], 1);
        __syncthreads();
        if (threadIdx.x < 8) blockhist[hb * 8 + threadIdx.x] = hh[threadIdx.x];
    }
}

// ---------- scatter: wave-parallel scan + ballot rank (no global atomics) ----------
__global__ void k_scatter(const int* __restrict__ pe, const int* __restrict__ blockhist,
                          int* __restrict__ list, int* __restrict__ cnt, int* __restrict__ basep) {
    __shared__ int boff[8];
    __shared__ int totS[8], exS[8];
    __shared__ int wavecnt[4 * 8];
    int t = threadIdx.x, w = t >> 6, l = t & 63;
    if (w == 0) {
        #pragma unroll
        for (int e = 0; e < 8; ++e) {
            int h = blockhist[l * 8 + e];
            int pref = h;
            #pragma unroll
            for (int off = 1; off < 64; off <<= 1) {
                int v = __shfl_up(pref, off, 64);
                pref += (l >= off) ? v : 0;
            }
            if (l == (int)blockIdx.x) exS[e] = pref - h;
            if (l == 63) totS[e] = pref;
        }
    }
    __syncthreads();
    if (t == 0) {
        int run = 0;
        #pragma unroll
        for (int e = 0; e < 8; ++e) {
            boff[e] = run + exS[e];
            if (blockIdx.x == 0) { basep[e] = run; cnt[e] = totS[e]; }
            run += totS[e];
        }
    }
    __syncthreads();
    int n = blockIdx.x * 256 + t;
    int e = pe[n];
    unsigned long long mymask = 0;
    #pragma unroll
    for (int r = 0; r < 8; ++r) {
        unsigned long long m = __ballot(e == r);
        if (e == r) mymask = m;
        if (l == r) wavecnt[w * 8 + r] = (int)__popcll(m);
    }
    __syncthreads();
    int off = 0;
    for (int w2 = 0; w2 < w; ++w2) off += wavecnt[w2 * 8 + e];
    unsigned long long ltmask = (1ull << l) - 1ull;
    int rank = (int)__popcll(mymask & ltmask);
    list[boff[e] + off + rank] = n;
}

// ---------- center (MFMA): reads fp32 ns directly, converts in-register ----------
__global__ __launch_bounds__(256, 4)
void k_center(const float* __restrict__ ns, const unsigned short* __restrict__ pewfrag,
              const int* __restrict__ list, const int* __restrict__ cnt,
              const int* __restrict__ base, unsigned short* __restrict__ center_bf) {
    int e = blockIdx.y;
    int c = cnt[e];
    int start = blockIdx.x * 16;
    if (start >= c) return;
    int w = threadIdx.x >> 6, l = threadIdx.x & 63;

    int rid = list[base[e] + min(start + (l & 15), c - 1)];

    float4v acc[2] = {};
    const unsigned short* pf = pewfrag + ((size_t)e << 15);
    #pragma unroll
    for (int ks = 0; ks < 8; ++ks) {
        short8 a = ld8bf(&ns[(size_t)rid * 256 + ks * 32 + ((l >> 4) << 3)]);
        #pragma unroll
        for (int ci = 0; ci < 2; ++ci) {
            int ct = w * 2 + ci;
            short8 b = *(const short8*)&pf[(((ks * 8 + ct) << 6) + l) * 8];
            acc[ci] = __builtin_amdgcn_mfma_f32_16x16x32_bf16(a, b, acc[ci], 0, 0, 0);
        }
    }
    #pragma unroll
    for (int reg = 0; reg < 4; ++reg) {
        int row16 = start + ((l >> 4) << 2) + reg;
        if (row16 < c) {
            int gid = list[base[e] + row16];
            #pragma unroll
            for (int ci = 0; ci < 2; ++ci)
                center_bf[(size_t)gid * 128 + (w * 2 + ci) * 16 + (l & 15)] = f2bf(acc[ci][reg]);
        }
    }
}

// ---------- final: transposed-scores phase B + R2's proven xs subtile layout ----------
// scores^T = mfma(A = qr-rows (qlds), B = X (xp regs)) -> S[rel][edge], edge = lane&15
// (lane already owns rv/ai). Selection: 3 cndmask + 1 shfl per t. Softmax: 2 exp +
// 8 shfl_xor. A-frag: 8 shfls from pre-selected md register.
// xs staging (per wave, 32 edges x 128 ch bf16, 8 KB), R2 subtile layout:
//   off(edge,ch) = (ch>>4)*512 + (edge>>2)*64 + ((edge&3)^((edge>>2)&3))*16 + (ch&15)
// Write from xp: lane owns edge=t*16+(l&15), ch = ks*32+(l>>4)*8+j (j=0..7) ->
//   ch>>4 = ks*2+(G>>1), ch&15 = (G&1)*8+j contiguous -> one aligned b128 per (t,ks).
// Bucket read: identical addressing to R2 (measured-at-floor conflicts).
#define QSTRIDE 1096
__global__ __launch_bounds__(256, 2)
void k_final(const unsigned short* __restrict__ center_bf,
             const unsigned short* __restrict__ BallQfrag,
             const unsigned short* __restrict__ RVFfrag,
             const int* __restrict__ adj, const int* __restrict__ rel,
             const float* __restrict__ fcb, float* __restrict__ out) {
    __shared__ unsigned short qlds[16 * QSTRIDE];            // ~35 KB
    __shared__ __align__(16) unsigned short xs[4][4096];     // 32 KB: per-wave X staging
    int w = threadIdx.x >> 6, l = threadIdx.x & 63;
    int n0 = blockIdx.x * 16;

    // ---- preload adjacency/relations for this wave's 4 nodes (index dep only on l&15)
    int aiq[4][2], rvq[4][2], rvrow[4][2];
    #pragma unroll
    for (int q = 0; q < 4; ++q) {
        int n = n0 + w * 4 + q;
        #pragma unroll
        for (int t = 0; t < 2; ++t) {
            aiq[q][t] = adj[n * DD + t * 16 + (l & 15)];
            rvq[q][t] = rel[n * DD + t * 16 + (l & 15)];
            rvrow[q][t] = aiq[q][t] > 0 ? aiq[q][t] - 1 : 0;
        }
    }

    // X prefetch for q=0 (lands under phase A): xp[t][ks] = X[edge t*16+(l&15)][ks*32+(l>>4)*8..+8]
    short8 xp[2][4];
    #pragma unroll
    for (int t = 0; t < 2; ++t)
        #pragma unroll
        for (int ks = 0; ks < 4; ++ks)
            xp[t][ks] = *(const short8*)&center_bf[(size_t)rvrow[0][t] * 128 + ks * 32 + ((l >> 4) << 3)];

    // phase A: qr tile (16 nodes x 1024) into LDS; wave w computes cols w*256..+256
    {
        short8 a[4];
        #pragma unroll
        for (int ks = 0; ks < 4; ++ks)
            a[ks] = *(const short8*)&center_bf[(size_t)(n0 + (l & 15)) * 128 + ks * 32 + ((l >> 4) << 3)];
        for (int ci = 0; ci < 16; ++ci) {
            int ct = w * 16 + ci;
            float4v acc = {};
            #pragma unroll
            for (int ks = 0; ks < 4; ++ks) {
                short8 b = *(const short8*)&BallQfrag[(((ks * 64 + ct) << 6) + l) * 8];
                acc = __builtin_amdgcn_mfma_f32_16x16x32_bf16(a[ks], b, acc, 0, 0, 0);
            }
            int r = ct >> 3;
            int ch = (ct & 7) * 16 + (l & 15);
            #pragma unroll
            for (int reg = 0; reg < 4; ++reg) {
                int rn = ((l >> 4) << 2) + reg;
                qlds[rn * QSTRIDE + r * 136 + ch] = f2bf(acc[reg]);
            }
        }
    }
    __syncthreads();

    unsigned short* xsw = &xs[w][0];

    // phase B: wave w handles nodes n0 + w*4 .. +4
    #pragma unroll
    for (int q = 0; q < 4; ++q) {
        int tn = w * 4 + q;
        int ai0 = aiq[q][0], ai1 = aiq[q][1];
        int rv0 = rvq[q][0], rv1 = rvq[q][1];

        // 1. write xs from xp into R2 subtile layout (one aligned b128 per (t,ks))
        {
            int G = l >> 4;
            #pragma unroll
            for (int t = 0; t < 2; ++t) {
                int edge = t * 16 + (l & 15);
                int est = edge >> 2;
                int slot = (edge & 3) ^ (est & 3);
                int base = est * 64 + slot * 16 + (G & 1) * 8;
                #pragma unroll
                for (int ks = 0; ks < 4; ++ks)
                    *(short8*)&xsw[(ks * 2 + (G >> 1)) * 512 + base] = xp[t][ks];
            }
        }

        // 2. scores^T: S[rel(m, dup x2)][edge n=l&15] = mfma(A=qb, B=xp)
        float4v sc[2] = {};
        #pragma unroll
        for (int ks = 0; ks < 4; ++ks) {
            short8 qb = *(const short8*)&qlds[tn * QSTRIDE + (l & 7) * 136 + ks * 32 + ((l >> 4) << 3)];
            sc[0] = __builtin_amdgcn_mfma_f32_16x16x32_bf16(qb, xp[0][ks], sc[0], 0, 0, 0);
            sc[1] = __builtin_amdgcn_mfma_f32_16x16x32_bf16(qb, xp[1][ks], sc[1], 0, 0, 0);
        }

        // 3. prefetch next q's X (after last xp use; hides under softmax+bucket)
        if (q < 3) {
            #pragma unroll
            for (int t = 0; t < 2; ++t)
                #pragma unroll
                for (int ks = 0; ks < 4; ++ks)
                    xp[t][ks] = *(const short8*)&center_bf[(size_t)rvrow[q + 1][t] * 128
                                                           + ks * 32 + ((l >> 4) << 3)];
        }

        // 4. select S[rv][own edge]: needed row rv -> group rv>>2, reg rv&3; source
        //    lane shares l&15 -> same rv -> in-lane reg-select then one shfl.
        float sel0, sel1;
        {
            int r = rv0;
            float v01 = (r & 1) ? sc[0][1] : sc[0][0];
            float v23 = (r & 1) ? sc[0][3] : sc[0][2];
            float regv = (r & 2) ? v23 : v01;
            float s = __shfl(regv, ((r >> 2) << 4) | (l & 15), 64);
            if (ai0 == 0) s = 0.f;
            if (r == 0) s = -1e9f;
            sel0 = s;
        }
        {
            int r = rv1;
            float v01 = (r & 1) ? sc[1][1] : sc[1][0];
            float v23 = (r & 1) ? sc[1][3] : sc[1][2];
            float regv = (r & 2) ? v23 : v01;
            float s = __shfl(regv, ((r >> 2) << 4) | (l & 15), 64);
            if (ai1 == 0) s = 0.f;
            if (r == 0) s = -1e9f;
            sel1 = s;
        }

        // 5. softmax over 32 edges = {t} x {16 lanes}; groups replicate identically
        float mx = fmaxf(sel0, sel1);
        mx = fmaxf(mx, __shfl_xor(mx, 1, 64));
        mx = fmaxf(mx, __shfl_xor(mx, 2, 64));
        mx = fmaxf(mx, __shfl_xor(mx, 4, 64));
        mx = fmaxf(mx, __shfl_xor(mx, 8, 64));
        float at0 = __expf(sel0 - mx);
        float at1 = __expf(sel1 - mx);
        float sm = at0 + at1;
        sm += __shfl_xor(sm, 1, 64);
        sm += __shfl_xor(sm, 2, 64);
        sm += __shfl_xor(sm, 4, 64);
        sm += __shfl_xor(sm, 8, 64);
        float inv = 1.0f / sm;
        at0 *= inv; at1 *= inv;
        if (ai0 == 0) at0 = 0.f;          // pad rows contribute 0
        if (ai1 == 0) at1 = 0.f;

        // 6. bucket A-frag via shfl: dest lane wants edge E=(l>>4)*8+jj held by
        //    source S=(l&48)|(((l>>4)&1)*8+jj); S pre-selects md by its own t,
        //    which equals the asker's E>>4 (same group).
        unsigned md0 = (unsigned)f2bf(at0) | ((unsigned)rv0 << 16);
        unsigned md1 = (unsigned)f2bf(at1) | ((unsigned)rv1 << 16);
        unsigned mdsel = (l >= 32) ? md1 : md0;
        unsigned aw[4];
        #pragma unroll
        for (int jp = 0; jp < 4; ++jp) {
            unsigned m0 = __shfl(mdsel, (l & 48) | (((l >> 4) & 1) * 8 + jp * 2), 64);
            unsigned m1 = __shfl(mdsel, (l & 48) | (((l >> 4) & 1) * 8 + jp * 2 + 1), 64);
            unsigned s0 = ((m0 >> 16) == (unsigned)(l & 15)) ? (m0 & 0xFFFFu) : 0u;
            unsigned s1 = ((m1 >> 16) == (unsigned)(l & 15)) ? (m1 & 0xFFFFu) : 0u;
            aw[jp] = s0 | (s1 << 16);
        }
        uint4v av = {aw[0], aw[1], aw[2], aw[3]};
        short8 afrag = __builtin_bit_cast(short8, av);

        // 7. bucket via MFMA: B-frag k=(l>>4)*8+jj (edge), n=l&15 (ch in ct tile);
        //    R2's proven read: xs[ct*512 + st*64 + ((jj&3)^(st&3))*16 + (l&15)],
        //    st = (l>>4)*2 + (jj>>2).
        #pragma unroll
        for (int ct = 0; ct < 8; ++ct) {
            unsigned short p[8];
            #pragma unroll
            for (int jj = 0; jj < 8; ++jj) {
                int st = (l >> 4) * 2 + (jj >> 2);
                int slot = (jj & 3) ^ (st & 3);
                p[jj] = xsw[ct * 512 + st * 64 + slot * 16 + (l & 15)];
            }
            uint4v bv = {(unsigned)p[0] | ((unsigned)p[1] << 16),
                         (unsigned)p[2] | ((unsigned)p[3] << 16),
                         (unsigned)p[4] | ((unsigned)p[5] << 16),
                         (unsigned)p[6] | ((unsigned)p[7] << 16)};
            float4v zc = {};
            float4v acc = __builtin_amdgcn_mfma_f32_16x16x32_bf16(
                afrag, __builtin_bit_cast(short8, bv), zc, 0, 0, 0);
            if (l < 32) {     // C rows 0..7 = relations; rows 8..15 are zero
                int rbase = (l >> 4) << 2;
                #pragma unroll
                for (int reg = 0; reg < 4; ++reg)
                    qlds[tn * QSTRIDE + (rbase + reg) * 136 + ct * 16 + (l & 15)] = f2bf(acc[reg]);
            }
        }
    }
    __syncthreads();

    // phase C: agg16x128 = bucket(16x1024, r-stride 136) @ RVF(1024x128), fused epilogue
    // A-operand hoisted: one ds_read per ks feeds both ci accumulators.
    {
        float4v acc[2] = {};
        #pragma unroll 4
        for (int ks = 0; ks < 32; ++ks) {
            short8 a = *(const short8*)&qlds[(l & 15) * QSTRIDE + (ks >> 2) * 136
                                             + (ks & 3) * 32 + ((l >> 4) << 3)];
            #pragma unroll
            for (int ci = 0; ci < 2; ++ci) {
                int ct = w * 2 + ci;
                short8 b = *(const short8*)&RVFfrag[(((ks * 8 + ct) << 6) + l) * 8];
                acc[ci] = __builtin_amdgcn_mfma_f32_16x16x32_bf16(a, b, acc[ci], 0, 0, 0);
            }
        }
        #pragma unroll
        for (int ci = 0; ci < 2; ++ci) {
            int ct = w * 2 + ci;
            int col = ct * 16 + (l & 15);
            float bb = fcb[col];
            #pragma unroll
            for (int reg = 0; reg < 4; ++reg) {
                int n = n0 + ((l >> 4) << 2) + reg;
                float v = acc[ci][reg] + bb;
                v = v > 0.f ? v : 0.f;
                out[(size_t)n * 128 + col] = bf2f(center_bf[(size_t)n * 128 + col]) + v;
            }
        }
    }
}

extern "C" void kernel_launch(void* const* d_in, const int* in_sizes, int n_in,
                              void* d_out, int out_size, void* d_ws, size_t ws_size,
                              hipStream_t stream) {
    const float* node_state = (const float*)d_in[0];
    const int*   adjacency  = (const int*)d_in[1];
    const int*   point_enc  = (const int*)d_in[2];
    const int*   relation   = (const int*)d_in[3];
    const float* pew        = (const float*)d_in[4];
    const float* relw       = (const float*)d_in[5];
    const float* qw         = (const float*)d_in[6];
    const float* kw         = (const float*)d_in[7];
    const float* vw         = (const float*)d_in[8];
    const float* fcw        = (const float*)d_in[9];
    const float* fcb        = (const float*)d_in[10];
    float* out = (float*)d_out;

    char* ws = (char*)d_ws;
    unsigned short* BallQfrag = (unsigned short*)ws;  ws += 128 * 1024 * 2;            // 256 KB
    unsigned short* RVFfrag   = (unsigned short*)ws;  ws += 1024 * 128 * 2;            // 256 KB
    unsigned short* center_bf = (unsigned short*)ws;  ws += (size_t)NNODE * 128 * 2;   // 4 MB
    unsigned short* pewfrag   = (unsigned short*)ws;  ws += 8 * 32768 * 2;             // 512 KB
    int* blockhist            = (int*)ws;             ws += 64 * 8 * 4;
    int* cnt                  = (int*)ws;             ws += 32;
    int* basep                = (int*)ws;             ws += 32;
    int* list                 = (int*)ws;             ws += NNODE * 4;                 // 64 KB

    k_setup<<<1152, 256, 0, stream>>>(pew, qw, kw, relw, vw, fcw, point_enc,
                                      pewfrag, BallQfrag, RVFfrag, blockhist);
    k_scatter<<<64, 256, 0, stream>>>(point_enc, blockhist, list, cnt, basep);
    k_center<<<dim3(192, 8), 256, 0, stream>>>(node_state, pewfrag, list, cnt, basep, center_bf);
    k_final<<<NNODE / 16, 256, 0, stream>>>(center_bf, BallQfrag, RVFfrag,
                                            adjacency, relation, fcb, out);
}

// Round 7
// 160.647 us; speedup vs baseline: 1.0546x; 1.0287x over previous
//
#include <hip/hip_runtime.h>

#define NNODE 16384
#define DD 32
#define INPC 256
#define UC 128
#define RC 8
#define EC 8

typedef __attribute__((ext_vector_type(8))) short short8;
typedef __attribute__((ext_vector_type(4))) float float4v;
typedef __attribute__((ext_vector_type(4))) unsigned uint4v;

__device__ __forceinline__ unsigned short f2bf(float f) {
    unsigned u = __builtin_bit_cast(unsigned, f);
    unsigned r = (u + 0x7FFFu + ((u >> 16) & 1u)) >> 16;   // RNE
    return (unsigned short)r;
}
__device__ __forceinline__ float bf2f(unsigned short s) { return __builtin_bit_cast(float, (unsigned)s << 16); }

// DPP quad-perm cross-lane (VALU pipe, ~4cy — avoids LDS-pipe ds_swizzle latency)
template <int CTRL>
__device__ __forceinline__ float dppq(float x) {
    return __builtin_bit_cast(float,
        __builtin_amdgcn_mov_dpp(__builtin_bit_cast(int, x), CTRL, 0xF, 0xF, true));
}
#define DPP_XOR1 0xB1   // quad_perm [1,0,3,2]
#define DPP_XOR2 0x4E   // quad_perm [2,3,0,1]

// load 8 consecutive fp32 and convert to a bf16 MFMA fragment half
__device__ __forceinline__ short8 ld8bf(const float* p) {
    float4 v0 = *(const float4*)p;
    float4 v1 = *(const float4*)(p + 4);
    short8 a;
    a[0] = (short)f2bf(v0.x); a[1] = (short)f2bf(v0.y);
    a[2] = (short)f2bf(v0.z); a[3] = (short)f2bf(v0.w);
    a[4] = (short)f2bf(v1.x); a[5] = (short)f2bf(v1.y);
    a[6] = (short)f2bf(v1.z); a[7] = (short)f2bf(v1.w);
    return a;
}

// B-fragment flat index for mfma_f32_16x16x32_bf16. nct = #16-col tiles.
__device__ __forceinline__ int bfrag_idx(int k, int col, int nct) {
    int ks = k >> 5, ct = col >> 4;
    int l = (((k >> 3) & 3) << 4) | (col & 15);
    return (((ks * nct + ct) << 6) + l) * 8 + (k & 7);
}

// ---------- setup: [0,1024) pew->frag | [1024,1088) prep (MFMA) | [1088,1152) hist ----------
__global__ void k_setup(const float* __restrict__ pew, const float* __restrict__ qw,
                        const float* __restrict__ kw, const float* __restrict__ relw,
                        const float* __restrict__ vw, const float* __restrict__ fcw,
                        const int* __restrict__ pe,
                        unsigned short* __restrict__ pewfrag,
                        unsigned short* __restrict__ BallQfrag, unsigned short* __restrict__ RVFfrag,
                        int* __restrict__ blockhist) {
    __shared__ unsigned short stage_s[128 * 132];   // ~33.8 KB: vw then fcw (bf16)
    __shared__ unsigned short mat_s[16 * 136];      // ~4.35 KB: P then RV (bf16)
    __shared__ int hh[8];
    int b = blockIdx.x;
    if (b < 1024) {                   // pew -> B-fragments (K=256, N=128 per entity)
        int id = b * 256 + threadIdx.x;
        int e = id >> 15, k = (id >> 7) & 255, col = id & 127;
        pewfrag[(e << 15) + bfrag_idx(k, col, 8)] = f2bf(pew[id]);
        return;
    }
    if (b < 1088) {                   // prep: all four small GEMMs via MFMA
        int pb = b - 1024;
        int r = pb & 7, i0 = (pb >> 3) * 16;
        int w = threadIdx.x >> 6, l = threadIdx.x & 63;
        int mrow = l & 15, kgrp = (l >> 4) << 3;
        const float* R = relw + r * (UC * UC);

        // ---- phase P: P rows i0..i0+16 = qw[i0..] @ kw^T
        float4v accP[2] = {};
        #pragma unroll
        for (int ks = 0; ks < 4; ++ks) {
            short8 a = ld8bf(&qw[(i0 + mrow) * UC + ks * 32 + kgrp]);
            #pragma unroll
            for (int ci = 0; ci < 2; ++ci) {
                int ct = w * 2 + ci;
                short8 bf = ld8bf(&kw[(ct * 16 + mrow) * UC + ks * 32 + kgrp]);
                accP[ci] = __builtin_amdgcn_mfma_f32_16x16x32_bf16(a, bf, accP[ci], 0, 0, 0);
            }
        }
        #pragma unroll
        for (int ci = 0; ci < 2; ++ci)
            #pragma unroll
            for (int reg = 0; reg < 4; ++reg) {
                int row = ((l >> 4) << 2) + reg;
                int col = (w * 2 + ci) * 16 + mrow;
                mat_s[row * 136 + col] = f2bf(accP[ci][reg] * (1.0f / 128.0f));
            }
        // stage vw (bf16, stride 132)
        for (int it = 0; it < 16; ++it) {
            int idx = it * 256 + threadIdx.x;      // float4 index
            int row = idx >> 5, col = (idx & 31) * 4;
            float4 v = *(const float4*)&vw[row * UC + col];
            uint2 o;
            o.x = (unsigned)f2bf(v.x) | ((unsigned)f2bf(v.y) << 16);
            o.y = (unsigned)f2bf(v.z) | ((unsigned)f2bf(v.w) << 16);
            *(uint2*)&stage_s[row * 132 + col] = o;
        }
        __syncthreads();

        // ---- phase M: M = P @ R^T ; phase RV: RV = R @ vw (interleaved)
        float4v accM[2] = {}, accV[2] = {};
        #pragma unroll
        for (int ks = 0; ks < 4; ++ks) {
            short8 aM = *(const short8*)&mat_s[mrow * 136 + ks * 32 + kgrp];
            short8 aV = ld8bf(&R[(i0 + mrow) * UC + ks * 32 + kgrp]);
            #pragma unroll
            for (int ci = 0; ci < 2; ++ci) {
                int ct = w * 2 + ci;
                short8 bM = ld8bf(&R[(ct * 16 + mrow) * UC + ks * 32 + kgrp]);
                accM[ci] = __builtin_amdgcn_mfma_f32_16x16x32_bf16(aM, bM, accM[ci], 0, 0, 0);
                uint4v pv;
                #pragma unroll
                for (int jp = 0; jp < 4; ++jp) {
                    unsigned e0 = stage_s[(ks * 32 + kgrp + jp * 2) * 132 + ct * 16 + mrow];
                    unsigned e1 = stage_s[(ks * 32 + kgrp + jp * 2 + 1) * 132 + ct * 16 + mrow];
                    pv[jp] = e0 | (e1 << 16);
                }
                accV[ci] = __builtin_amdgcn_mfma_f32_16x16x32_bf16(
                    aV, __builtin_bit_cast(short8, pv), accV[ci], 0, 0, 0);
            }
        }
        #pragma unroll
        for (int ci = 0; ci < 2; ++ci)
            #pragma unroll
            for (int reg = 0; reg < 4; ++reg) {
                int i = i0 + ((l >> 4) << 2) + reg;
                int col = r * 128 + (w * 2 + ci) * 16 + mrow;
                BallQfrag[bfrag_idx(i, col, 64)] = f2bf(accM[ci][reg]);
            }
        __syncthreads();   // mat_s / stage_s reads done
        // store RV rows; stage fcw
        #pragma unroll
        for (int ci = 0; ci < 2; ++ci)
            #pragma unroll
            for (int reg = 0; reg < 4; ++reg)
                mat_s[(((l >> 4) << 2) + reg) * 136 + (w * 2 + ci) * 16 + mrow] = f2bf(accV[ci][reg]);
        for (int it = 0; it < 16; ++it) {
            int idx = it * 256 + threadIdx.x;
            int row = idx >> 5, col = (idx & 31) * 4;
            float4 v = *(const float4*)&fcw[row * UC + col];
            uint2 o;
            o.x = (unsigned)f2bf(v.x) | ((unsigned)f2bf(v.y) << 16);
            o.y = (unsigned)f2bf(v.z) | ((unsigned)f2bf(v.w) << 16);
            *(uint2*)&stage_s[row * 132 + col] = o;
        }
        __syncthreads();

        // ---- phase RVF: RVF = RV @ fcw
        float4v accF[2] = {};
        #pragma unroll
        for (int ks = 0; ks < 4; ++ks) {
            short8 aF = *(const short8*)&mat_s[mrow * 136 + ks * 32 + kgrp];
            #pragma unroll
            for (int ci = 0; ci < 2; ++ci) {
                int ct = w * 2 + ci;
                uint4v pv;
                #pragma unroll
                for (int jp = 0; jp < 4; ++jp) {
                    unsigned e0 = stage_s[(ks * 32 + kgrp + jp * 2) * 132 + ct * 16 + mrow];
                    unsigned e1 = stage_s[(ks * 32 + kgrp + jp * 2 + 1) * 132 + ct * 16 + mrow];
                    pv[jp] = e0 | (e1 << 16);
                }
                accF[ci] = __builtin_amdgcn_mfma_f32_16x16x32_bf16(
                    aF, __builtin_bit_cast(short8, pv), accF[ci], 0, 0, 0);
            }
        }
        #pragma unroll
        for (int ci = 0; ci < 2; ++ci)
            #pragma unroll
            for (int reg = 0; reg < 4; ++reg) {
                int i = i0 + ((l >> 4) << 2) + reg;
                int col = (w * 2 + ci) * 16 + mrow;
                RVFfrag[bfrag_idx(r * 128 + i, col, 8)] = f2bf(accF[ci][reg]);
            }
        return;
    }
    {   // hist
        int hb = b - 1088;
        if (threadIdx.x < 8) hh[threadIdx.x] = 0;
        __syncthreads();
        atomicAdd(&hh[pe[hb * 256 + threadIdx.x]], 1);
        __syncthreads();
        if (threadIdx.x < 8) blockhist[hb * 8 + threadIdx.x] = hh[threadIdx.x];
    }
}

// ---------- scatter: wave-parallel scan + ballot rank (no global atomics) ----------
__global__ void k_scatter(const int* __restrict__ pe, const int* __restrict__ blockhist,
                          int* __restrict__ list, int* __restrict__ cnt, int* __restrict__ basep) {
    __shared__ int boff[8];
    __shared__ int totS[8], exS[8];
    __shared__ int wavecnt[4 * 8];
    int t = threadIdx.x, w = t >> 6, l = t & 63;
    if (w == 0) {
        #pragma unroll
        for (int e = 0; e < 8; ++e) {
            int h = blockhist[l * 8 + e];
            int pref = h;
            #pragma unroll
            for (int off = 1; off < 64; off <<= 1) {
                int v = __shfl_up(pref, off, 64);
                pref += (l >= off) ? v : 0;
            }
            if (l == (int)blockIdx.x) exS[e] = pref - h;
            if (l == 63) totS[e] = pref;
        }
    }
    __syncthreads();
    if (t == 0) {
        int run = 0;
        #pragma unroll
        for (int e = 0; e < 8; ++e) {
            boff[e] = run + exS[e];
            if (blockIdx.x == 0) { basep[e] = run; cnt[e] = totS[e]; }
            run += totS[e];
        }
    }
    __syncthreads();
    int n = blockIdx.x * 256 + t;
    int e = pe[n];
    unsigned long long mymask = 0;
    #pragma unroll
    for (int r = 0; r < 8; ++r) {
        unsigned long long m = __ballot(e == r);
        if (e == r) mymask = m;
        if (l == r) wavecnt[w * 8 + r] = (int)__popcll(m);
    }
    __syncthreads();
    int off = 0;
    for (int w2 = 0; w2 < w; ++w2) off += wavecnt[w2 * 8 + e];
    unsigned long long ltmask = (1ull << l) - 1ull;
    int rank = (int)__popcll(mymask & ltmask);
    list[boff[e] + off + rank] = n;
}

// ---------- center (MFMA): reads fp32 ns directly, converts in-register ----------
__global__ __launch_bounds__(256, 4)
void k_center(const float* __restrict__ ns, const unsigned short* __restrict__ pewfrag,
              const int* __restrict__ list, const int* __restrict__ cnt,
              const int* __restrict__ base, unsigned short* __restrict__ center_bf) {
    int e = blockIdx.y;
    int c = cnt[e];
    int start = blockIdx.x * 16;
    if (start >= c) return;
    int w = threadIdx.x >> 6, l = threadIdx.x & 63;

    int rid = list[base[e] + min(start + (l & 15), c - 1)];

    float4v acc[2] = {};
    const unsigned short* pf = pewfrag + ((size_t)e << 15);
    #pragma unroll
    for (int ks = 0; ks < 8; ++ks) {
        short8 a = ld8bf(&ns[(size_t)rid * 256 + ks * 32 + ((l >> 4) << 3)]);
        #pragma unroll
        for (int ci = 0; ci < 2; ++ci) {
            int ct = w * 2 + ci;
            short8 b = *(const short8*)&pf[(((ks * 8 + ct) << 6) + l) * 8];
            acc[ci] = __builtin_amdgcn_mfma_f32_16x16x32_bf16(a, b, acc[ci], 0, 0, 0);
        }
    }
    #pragma unroll
    for (int reg = 0; reg < 4; ++reg) {
        int row16 = start + ((l >> 4) << 2) + reg;
        if (row16 < c) {
            int gid = list[base[e] + row16];
            #pragma unroll
            for (int ci = 0; ci < 2; ++ci)
                center_bf[(size_t)gid * 128 + (w * 2 + ci) * 16 + (l & 15)] = f2bf(acc[ci][reg]);
        }
    }
}

// ---------- final: transposed-scores phase B, short-chain softmax ----------
// scores^T = mfma(A = qr-rows (qlds), B = X (xp regs)) -> S[rel][edge], edge = lane&15.
// Softmax: NO max subtraction (shift-invariant; sel clamped at 60 so exp <= 1e26 in
// f32; masked -1e9 -> exp = 0 exactly; sm floor guards /0). Sum tree: xor1/xor2 via
// DPP quad_perm (VALU pipe), xor4/xor8 via shfl. Chain per q: 1 bperm -> exp ->
// {dpp,dpp,swz,swz} -> rcp -> pack -> 8 parallel bperms -> bucket MFMA.
// xs staging: R2's measured-at-floor subtile layout (see R6).
#define QSTRIDE 1096
__global__ __launch_bounds__(256, 2)
void k_final(const unsigned short* __restrict__ center_bf,
             const unsigned short* __restrict__ BallQfrag,
             const unsigned short* __restrict__ RVFfrag,
             const int* __restrict__ adj, const int* __restrict__ rel,
             const float* __restrict__ fcb, float* __restrict__ out) {
    __shared__ unsigned short qlds[16 * QSTRIDE];            // ~35 KB
    __shared__ __align__(16) unsigned short xs[4][4096];     // 32 KB: per-wave X staging
    int w = threadIdx.x >> 6, l = threadIdx.x & 63;
    int n0 = blockIdx.x * 16;

    // ---- preload adjacency/relations for this wave's 4 nodes (index dep only on l&15)
    int aiq[4][2], rvq[4][2], rvrow[4][2];
    #pragma unroll
    for (int q = 0; q < 4; ++q) {
        int n = n0 + w * 4 + q;
        #pragma unroll
        for (int t = 0; t < 2; ++t) {
            aiq[q][t] = adj[n * DD + t * 16 + (l & 15)];
            rvq[q][t] = rel[n * DD + t * 16 + (l & 15)];
            rvrow[q][t] = aiq[q][t] > 0 ? aiq[q][t] - 1 : 0;
        }
    }

    // X prefetch for q=0 (lands under phase A): xp[t][ks] = X[edge t*16+(l&15)][ks*32+(l>>4)*8..+8]
    short8 xp[2][4];
    #pragma unroll
    for (int t = 0; t < 2; ++t)
        #pragma unroll
        for (int ks = 0; ks < 4; ++ks)
            xp[t][ks] = *(const short8*)&center_bf[(size_t)rvrow[0][t] * 128 + ks * 32 + ((l >> 4) << 3)];

    // phase A: qr tile (16 nodes x 1024) into LDS; wave w computes cols w*256..+256
    {
        short8 a[4];
        #pragma unroll
        for (int ks = 0; ks < 4; ++ks)
            a[ks] = *(const short8*)&center_bf[(size_t)(n0 + (l & 15)) * 128 + ks * 32 + ((l >> 4) << 3)];
        for (int ci = 0; ci < 16; ++ci) {
            int ct = w * 16 + ci;
            float4v acc = {};
            #pragma unroll
            for (int ks = 0; ks < 4; ++ks) {
                short8 b = *(const short8*)&BallQfrag[(((ks * 64 + ct) << 6) + l) * 8];
                acc = __builtin_amdgcn_mfma_f32_16x16x32_bf16(a[ks], b, acc, 0, 0, 0);
            }
            int r = ct >> 3;
            int ch = (ct & 7) * 16 + (l & 15);
            #pragma unroll
            for (int reg = 0; reg < 4; ++reg) {
                int rn = ((l >> 4) << 2) + reg;
                qlds[rn * QSTRIDE + r * 136 + ch] = f2bf(acc[reg]);
            }
        }
    }
    __syncthreads();

    unsigned short* xsw = &xs[w][0];

    // phase B: wave w handles nodes n0 + w*4 .. +4
    #pragma unroll
    for (int q = 0; q < 4; ++q) {
        int tn = w * 4 + q;
        int ai0 = aiq[q][0], ai1 = aiq[q][1];
        int rv0 = rvq[q][0], rv1 = rvq[q][1];

        // 1. write xs from xp into R2 subtile layout (one aligned b128 per (t,ks))
        {
            int G = l >> 4;
            #pragma unroll
            for (int t = 0; t < 2; ++t) {
                int edge = t * 16 + (l & 15);
                int est = edge >> 2;
                int slot = (edge & 3) ^ (est & 3);
                int base = est * 64 + slot * 16 + (G & 1) * 8;
                #pragma unroll
                for (int ks = 0; ks < 4; ++ks)
                    *(short8*)&xsw[(ks * 2 + (G >> 1)) * 512 + base] = xp[t][ks];
            }
        }

        // 2. scores^T: S[rel(m, dup x2)][edge n=l&15] = mfma(A=qb, B=xp)
        float4v sc[2] = {};
        #pragma unroll
        for (int ks = 0; ks < 4; ++ks) {
            short8 qb = *(const short8*)&qlds[tn * QSTRIDE + (l & 7) * 136 + ks * 32 + ((l >> 4) << 3)];
            sc[0] = __builtin_amdgcn_mfma_f32_16x16x32_bf16(qb, xp[0][ks], sc[0], 0, 0, 0);
            sc[1] = __builtin_amdgcn_mfma_f32_16x16x32_bf16(qb, xp[1][ks], sc[1], 0, 0, 0);
        }

        // 3. prefetch next q's X (after last xp use; hides under softmax+bucket)
        if (q < 3) {
            #pragma unroll
            for (int t = 0; t < 2; ++t)
                #pragma unroll
                for (int ks = 0; ks < 4; ++ks)
                    xp[t][ks] = *(const short8*)&center_bf[(size_t)rvrow[q + 1][t] * 128
                                                           + ks * 32 + ((l >> 4) << 3)];
        }

        // 4. select S[rv][own edge]: needed row rv -> group rv>>2, reg rv&3; source
        //    lane shares l&15 -> same rv -> in-lane reg-select then one shfl.
        float sel0, sel1;
        {
            int r = rv0;
            float v01 = (r & 1) ? sc[0][1] : sc[0][0];
            float v23 = (r & 1) ? sc[0][3] : sc[0][2];
            float regv = (r & 2) ? v23 : v01;
            float s = __shfl(regv, ((r >> 2) << 4) | (l & 15), 64);
            if (ai0 == 0) s = 0.f;
            if (r == 0) s = -1e9f;
            sel0 = fminf(s, 60.f);     // overflow guard for exp (keeps -1e9)
        }
        {
            int r = rv1;
            float v01 = (r & 1) ? sc[1][1] : sc[1][0];
            float v23 = (r & 1) ? sc[1][3] : sc[1][2];
            float regv = (r & 2) ? v23 : v01;
            float s = __shfl(regv, ((r >> 2) << 4) | (l & 15), 64);
            if (ai1 == 0) s = 0.f;
            if (r == 0) s = -1e9f;
            sel1 = fminf(s, 60.f);
        }

        // 5. softmax (no max-shift): exp -> sum tree (2 DPP + 2 shfl) -> normalize
        float at0 = __expf(sel0);
        float at1 = __expf(sel1);
        float sm = at0 + at1;
        sm += dppq<DPP_XOR1>(sm);
        sm += dppq<DPP_XOR2>(sm);
        sm += __shfl_xor(sm, 4, 64);
        sm += __shfl_xor(sm, 8, 64);
        float inv = 1.0f / fmaxf(sm, 1e-30f);
        at0 *= inv; at1 *= inv;
        if (ai0 == 0) at0 = 0.f;          // pad rows contribute 0
        if (ai1 == 0) at1 = 0.f;

        // 6. bucket A-frag via shfl: dest lane wants edge E=(l>>4)*8+jj held by
        //    source S=(l&48)|(((l>>4)&1)*8+jj); S pre-selects md by its own t,
        //    which equals the asker's E>>4 (same group).
        unsigned md0 = (unsigned)f2bf(at0) | ((unsigned)rv0 << 16);
        unsigned md1 = (unsigned)f2bf(at1) | ((unsigned)rv1 << 16);
        unsigned mdsel = (l >= 32) ? md1 : md0;
        unsigned aw[4];
        #pragma unroll
        for (int jp = 0; jp < 4; ++jp) {
            unsigned m0 = __shfl(mdsel, (l & 48) | (((l >> 4) & 1) * 8 + jp * 2), 64);
            unsigned m1 = __shfl(mdsel, (l & 48) | (((l >> 4) & 1) * 8 + jp * 2 + 1), 64);
            unsigned s0 = ((m0 >> 16) == (unsigned)(l & 15)) ? (m0 & 0xFFFFu) : 0u;
            unsigned s1 = ((m1 >> 16) == (unsigned)(l & 15)) ? (m1 & 0xFFFFu) : 0u;
            aw[jp] = s0 | (s1 << 16);
        }
        uint4v av = {aw[0], aw[1], aw[2], aw[3]};
        short8 afrag = __builtin_bit_cast(short8, av);

        // 7. bucket via MFMA: B-frag k=(l>>4)*8+jj (edge), n=l&15 (ch in ct tile);
        //    R2's proven read: xs[ct*512 + st*64 + ((jj&3)^(st&3))*16 + (l&15)],
        //    st = (l>>4)*2 + (jj>>2).
        #pragma unroll
        for (int ct = 0; ct < 8; ++ct) {
            unsigned short p[8];
            #pragma unroll
            for (int jj = 0; jj < 8; ++jj) {
                int st = (l >> 4) * 2 + (jj >> 2);
                int slot = (jj & 3) ^ (st & 3);
                p[jj] = xsw[ct * 512 + st * 64 + slot * 16 + (l & 15)];
            }
            uint4v bv = {(unsigned)p[0] | ((unsigned)p[1] << 16),
                         (unsigned)p[2] | ((unsigned)p[3] << 16),
                         (unsigned)p[4] | ((unsigned)p[5] << 16),
                         (unsigned)p[6] | ((unsigned)p[7] << 16)};
            float4v zc = {};
            float4v acc = __builtin_amdgcn_mfma_f32_16x16x32_bf16(
                afrag, __builtin_bit_cast(short8, bv), zc, 0, 0, 0);
            if (l < 32) {     // C rows 0..7 = relations; rows 8..15 are zero
                int rbase = (l >> 4) << 2;
                #pragma unroll
                for (int reg = 0; reg < 4; ++reg)
                    qlds[tn * QSTRIDE + (rbase + reg) * 136 + ct * 16 + (l & 15)] = f2bf(acc[reg]);
            }
        }
    }
    __syncthreads();

    // phase C: agg16x128 = bucket(16x1024, r-stride 136) @ RVF(1024x128), fused epilogue
    // A-operand hoisted: one ds_read per ks feeds both ci accumulators.
    {
        float4v acc[2] = {};
        #pragma unroll 4
        for (int ks = 0; ks < 32; ++ks) {
            short8 a = *(const short8*)&qlds[(l & 15) * QSTRIDE + (ks >> 2) * 136
                                             + (ks & 3) * 32 + ((l >> 4) << 3)];
            #pragma unroll
            for (int ci = 0; ci < 2; ++ci) {
                int ct = w * 2 + ci;
                short8 b = *(const short8*)&RVFfrag[(((ks * 8 + ct) << 6) + l) * 8];
                acc[ci] = __builtin_amdgcn_mfma_f32_16x16x32_bf16(a, b, acc[ci], 0, 0, 0);
            }
        }
        #pragma unroll
        for (int ci = 0; ci < 2; ++ci) {
            int ct = w * 2 + ci;
            int col = ct * 16 + (l & 15);
            float bb = fcb[col];
            #pragma unroll
            for (int reg = 0; reg < 4; ++reg) {
                int n = n0 + ((l >> 4) << 2) + reg;
                float v = acc[ci][reg] + bb;
                v = v > 0.f ? v : 0.f;
                out[(size_t)n * 128 + col] = bf2f(center_bf[(size_t)n * 128 + col]) + v;
            }
        }
    }
}

extern "C" void kernel_launch(void* const* d_in, const int* in_sizes, int n_in,
                              void* d_out, int out_size, void* d_ws, size_t ws_size,
                              hipStream_t stream) {
    const float* node_state = (const float*)d_in[0];
    const int*   adjacency  = (const int*)d_in[1];
    const int*   point_enc  = (const int*)d_in[2];
    const int*   relation   = (const int*)d_in[3];
    const float* pew        = (const float*)d_in[4];
    const float* relw       = (const float*)d_in[5];
    const float* qw         = (const float*)d_in[6];
    const float* kw         = (const float*)d_in[7];
    const float* vw         = (const float*)d_in[8];
    const float* fcw        = (const float*)d_in[9];
    const float* fcb        = (const float*)d_in[10];
    float* out = (float*)d_out;

    char* ws = (char*)d_ws;
    unsigned short* BallQfrag = (unsigned short*)ws;  ws += 128 * 1024 * 2;            // 256 KB
    unsigned short* RVFfrag   = (unsigned short*)ws;  ws += 1024 * 128 * 2;            // 256 KB
    unsigned short* center_bf = (unsigned short*)ws;  ws += (size_t)NNODE * 128 * 2;   // 4 MB
    unsigned short* pewfrag   = (unsigned short*)ws;  ws += 8 * 32768 * 2;             // 512 KB
    int* blockhist            = (int*)ws;             ws += 64 * 8 * 4;
    int* cnt                  = (int*)ws;             ws += 32;
    int* basep                = (int*)ws;             ws += 32;
    int* list                 = (int*)ws;             ws += NNODE * 4;                 // 64 KB

    k_setup<<<1152, 256, 0, stream>>>(pew, qw, kw, relw, vw, fcw, point_enc,
                                      pewfrag, BallQfrag, RVFfrag, blockhist);
    k_scatter<<<64, 256, 0, stream>>>(point_enc, blockhist, list, cnt, basep);
    k_center<<<dim3(192, 8), 256, 0, stream>>>(node_state, pewfrag, list, cnt, basep, center_bf);
    k_final<<<NNODE / 16, 256, 0, stream>>>(center_bf, BallQfrag, RVFfrag,
                                            adjacency, relation, fcb, out);
}

// Round 9
// 159.200 us; speedup vs baseline: 1.0641x; 1.0091x over previous
//
#include <hip/hip_runtime.h>

#define NNODE 16384
#define DD 32
#define INPC 256
#define UC 128
#define RC 8
#define EC 8

typedef __attribute__((ext_vector_type(8))) short short8;
typedef __attribute__((ext_vector_type(4))) float float4v;
typedef __attribute__((ext_vector_type(4))) unsigned uint4v;

__device__ __forceinline__ unsigned short f2bf(float f) {
    unsigned u = __builtin_bit_cast(unsigned, f);
    unsigned r = (u + 0x7FFFu + ((u >> 16) & 1u)) >> 16;   // RNE
    return (unsigned short)r;
}
__device__ __forceinline__ float bf2f(unsigned short s) { return __builtin_bit_cast(float, (unsigned)s << 16); }

// DPP quad-perm cross-lane (VALU pipe, ~4cy — avoids LDS-pipe ds_swizzle latency)
template <int CTRL>
__device__ __forceinline__ float dppq(float x) {
    return __builtin_bit_cast(float,
        __builtin_amdgcn_mov_dpp(__builtin_bit_cast(int, x), CTRL, 0xF, 0xF, true));
}
#define DPP_XOR1 0xB1   // quad_perm [1,0,3,2]
#define DPP_XOR2 0x4E   // quad_perm [2,3,0,1]

// load 8 consecutive fp32 and convert to a bf16 MFMA fragment half
__device__ __forceinline__ short8 ld8bf(const float* p) {
    float4 v0 = *(const float4*)p;
    float4 v1 = *(const float4*)(p + 4);
    short8 a;
    a[0] = (short)f2bf(v0.x); a[1] = (short)f2bf(v0.y);
    a[2] = (short)f2bf(v0.z); a[3] = (short)f2bf(v0.w);
    a[4] = (short)f2bf(v1.x); a[5] = (short)f2bf(v1.y);
    a[6] = (short)f2bf(v1.z); a[7] = (short)f2bf(v1.w);
    return a;
}

// B-fragment flat index for mfma_f32_16x16x32_bf16. nct = #16-col tiles.
__device__ __forceinline__ int bfrag_idx(int k, int col, int nct) {
    int ks = k >> 5, ct = col >> 4;
    int l = (((k >> 3) & 3) << 4) | (col & 15);
    return (((ks * nct + ct) << 6) + l) * 8 + (k & 7);
}

// ---------- setup: [0,1024) pew->frag | [1024,1088) prep (MFMA) | [1088,1152) hist ----------
__global__ void k_setup(const float* __restrict__ pew, const float* __restrict__ qw,
                        const float* __restrict__ kw, const float* __restrict__ relw,
                        const float* __restrict__ vw, const float* __restrict__ fcw,
                        const int* __restrict__ pe,
                        unsigned short* __restrict__ pewfrag,
                        unsigned short* __restrict__ BallQfrag, unsigned short* __restrict__ RVFfrag,
                        int* __restrict__ blockhist) {
    __shared__ unsigned short stage_s[128 * 132];   // ~33.8 KB: vw then fcw (bf16)
    __shared__ unsigned short mat_s[16 * 136];      // ~4.35 KB: P then RV (bf16)
    __shared__ int hh[8];
    int b = blockIdx.x;
    if (b < 1024) {                   // pew -> B-fragments (K=256, N=128 per entity)
        int id = b * 256 + threadIdx.x;
        int e = id >> 15, k = (id >> 7) & 255, col = id & 127;
        pewfrag[(e << 15) + bfrag_idx(k, col, 8)] = f2bf(pew[id]);
        return;
    }
    if (b < 1088) {                   // prep: all four small GEMMs via MFMA
        int pb = b - 1024;
        int r = pb & 7, i0 = (pb >> 3) * 16;
        int w = threadIdx.x >> 6, l = threadIdx.x & 63;
        int mrow = l & 15, kgrp = (l >> 4) << 3;
        const float* R = relw + r * (UC * UC);

        // ---- phase P: P rows i0..i0+16 = qw[i0..] @ kw^T
        float4v accP[2] = {};
        #pragma unroll
        for (int ks = 0; ks < 4; ++ks) {
            short8 a = ld8bf(&qw[(i0 + mrow) * UC + ks * 32 + kgrp]);
            #pragma unroll
            for (int ci = 0; ci < 2; ++ci) {
                int ct = w * 2 + ci;
                short8 bf = ld8bf(&kw[(ct * 16 + mrow) * UC + ks * 32 + kgrp]);
                accP[ci] = __builtin_amdgcn_mfma_f32_16x16x32_bf16(a, bf, accP[ci], 0, 0, 0);
            }
        }
        #pragma unroll
        for (int ci = 0; ci < 2; ++ci)
            #pragma unroll
            for (int reg = 0; reg < 4; ++reg) {
                int row = ((l >> 4) << 2) + reg;
                int col = (w * 2 + ci) * 16 + mrow;
                mat_s[row * 136 + col] = f2bf(accP[ci][reg] * (1.0f / 128.0f));
            }
        // stage vw (bf16, stride 132)
        for (int it = 0; it < 16; ++it) {
            int idx = it * 256 + threadIdx.x;      // float4 index
            int row = idx >> 5, col = (idx & 31) * 4;
            float4 v = *(const float4*)&vw[row * UC + col];
            uint2 o;
            o.x = (unsigned)f2bf(v.x) | ((unsigned)f2bf(v.y) << 16);
            o.y = (unsigned)f2bf(v.z) | ((unsigned)f2bf(v.w) << 16);
            *(uint2*)&stage_s[row * 132 + col] = o;
        }
        __syncthreads();

        // ---- phase M: M = P @ R^T ; phase RV: RV = R @ vw (interleaved)
        float4v accM[2] = {}, accV[2] = {};
        #pragma unroll
        for (int ks = 0; ks < 4; ++ks) {
            short8 aM = *(const short8*)&mat_s[mrow * 136 + ks * 32 + kgrp];
            short8 aV = ld8bf(&R[(i0 + mrow) * UC + ks * 32 + kgrp]);
            #pragma unroll
            for (int ci = 0; ci < 2; ++ci) {
                int ct = w * 2 + ci;
                short8 bM = ld8bf(&R[(ct * 16 + mrow) * UC + ks * 32 + kgrp]);
                accM[ci] = __builtin_amdgcn_mfma_f32_16x16x32_bf16(aM, bM, accM[ci], 0, 0, 0);
                uint4v pv;
                #pragma unroll
                for (int jp = 0; jp < 4; ++jp) {
                    unsigned e0 = stage_s[(ks * 32 + kgrp + jp * 2) * 132 + ct * 16 + mrow];
                    unsigned e1 = stage_s[(ks * 32 + kgrp + jp * 2 + 1) * 132 + ct * 16 + mrow];
                    pv[jp] = e0 | (e1 << 16);
                }
                accV[ci] = __builtin_amdgcn_mfma_f32_16x16x32_bf16(
                    aV, __builtin_bit_cast(short8, pv), accV[ci], 0, 0, 0);
            }
        }
        #pragma unroll
        for (int ci = 0; ci < 2; ++ci)
            #pragma unroll
            for (int reg = 0; reg < 4; ++reg) {
                int i = i0 + ((l >> 4) << 2) + reg;
                int col = r * 128 + (w * 2 + ci) * 16 + mrow;
                BallQfrag[bfrag_idx(i, col, 64)] = f2bf(accM[ci][reg]);
            }
        __syncthreads();   // mat_s / stage_s reads done
        // store RV rows; stage fcw
        #pragma unroll
        for (int ci = 0; ci < 2; ++ci)
            #pragma unroll
            for (int reg = 0; reg < 4; ++reg)
                mat_s[(((l >> 4) << 2) + reg) * 136 + (w * 2 + ci) * 16 + mrow] = f2bf(accV[ci][reg]);
        for (int it = 0; it < 16; ++it) {
            int idx = it * 256 + threadIdx.x;
            int row = idx >> 5, col = (idx & 31) * 4;
            float4 v = *(const float4*)&fcw[row * UC + col];
            uint2 o;
            o.x = (unsigned)f2bf(v.x) | ((unsigned)f2bf(v.y) << 16);
            o.y = (unsigned)f2bf(v.z) | ((unsigned)f2bf(v.w) << 16);
            *(uint2*)&stage_s[row * 132 + col] = o;
        }
        __syncthreads();

        // ---- phase RVF: RVF = RV @ fcw
        float4v accF[2] = {};
        #pragma unroll
        for (int ks = 0; ks < 4; ++ks) {
            short8 aF = *(const short8*)&mat_s[mrow * 136 + ks * 32 + kgrp];
            #pragma unroll
            for (int ci = 0; ci < 2; ++ci) {
                int ct = w * 2 + ci;
                uint4v pv;
                #pragma unroll
                for (int jp = 0; jp < 4; ++jp) {
                    unsigned e0 = stage_s[(ks * 32 + kgrp + jp * 2) * 132 + ct * 16 + mrow];
                    unsigned e1 = stage_s[(ks * 32 + kgrp + jp * 2 + 1) * 132 + ct * 16 + mrow];
                    pv[jp] = e0 | (e1 << 16);
                }
                accF[ci] = __builtin_amdgcn_mfma_f32_16x16x32_bf16(
                    aF, __builtin_bit_cast(short8, pv), accF[ci], 0, 0, 0);
            }
        }
        #pragma unroll
        for (int ci = 0; ci < 2; ++ci)
            #pragma unroll
            for (int reg = 0; reg < 4; ++reg) {
                int i = i0 + ((l >> 4) << 2) + reg;
                int col = (w * 2 + ci) * 16 + mrow;
                RVFfrag[bfrag_idx(r * 128 + i, col, 8)] = f2bf(accF[ci][reg]);
            }
        return;
    }
    {   // hist
        int hb = b - 1088;
        if (threadIdx.x < 8) hh[threadIdx.x] = 0;
        __syncthreads();
        atomicAdd(&hh[pe[hb * 256 + threadIdx.x]], 1);
        __syncthreads();
        if (threadIdx.x < 8) blockhist[hb * 8 + threadIdx.x] = hh[threadIdx.x];
    }
}

// ---------- scatter: wave-parallel scan + ballot rank (no global atomics) ----------
__global__ void k_scatter(const int* __restrict__ pe, const int* __restrict__ blockhist,
                          int* __restrict__ list, int* __restrict__ cnt, int* __restrict__ basep) {
    __shared__ int boff[8];
    __shared__ int totS[8], exS[8];
    __shared__ int wavecnt[4 * 8];
    int t = threadIdx.x, w = t >> 6, l = t & 63;
    if (w == 0) {
        #pragma unroll
        for (int e = 0; e < 8; ++e) {
            int h = blockhist[l * 8 + e];
            int pref = h;
            #pragma unroll
            for (int off = 1; off < 64; off <<= 1) {
                int v = __shfl_up(pref, off, 64);
                pref += (l >= off) ? v : 0;
            }
            if (l == (int)blockIdx.x) exS[e] = pref - h;
            if (l == 63) totS[e] = pref;
        }
    }
    __syncthreads();
    if (t == 0) {
        int run = 0;
        #pragma unroll
        for (int e = 0; e < 8; ++e) {
            boff[e] = run + exS[e];
            if (blockIdx.x == 0) { basep[e] = run; cnt[e] = totS[e]; }
            run += totS[e];
        }
    }
    __syncthreads();
    int n = blockIdx.x * 256 + t;
    int e = pe[n];
    unsigned long long mymask = 0;
    #pragma unroll
    for (int r = 0; r < 8; ++r) {
        unsigned long long m = __ballot(e == r);
        if (e == r) mymask = m;
        if (l == r) wavecnt[w * 8 + r] = (int)__popcll(m);
    }
    __syncthreads();
    int off = 0;
    for (int w2 = 0; w2 < w; ++w2) off += wavecnt[w2 * 8 + e];
    unsigned long long ltmask = (1ull << l) - 1ull;
    int rank = (int)__popcll(mymask & ltmask);
    list[boff[e] + off + rank] = n;
}

// ---------- center (MFMA): reads fp32 ns directly, converts in-register ----------
__global__ __launch_bounds__(256, 4)
void k_center(const float* __restrict__ ns, const unsigned short* __restrict__ pewfrag,
              const int* __restrict__ list, const int* __restrict__ cnt,
              const int* __restrict__ base, unsigned short* __restrict__ center_bf) {
    int e = blockIdx.y;
    int c = cnt[e];
    int start = blockIdx.x * 16;
    if (start >= c) return;
    int w = threadIdx.x >> 6, l = threadIdx.x & 63;

    int rid = list[base[e] + min(start + (l & 15), c - 1)];

    float4v acc[2] = {};
    const unsigned short* pf = pewfrag + ((size_t)e << 15);
    #pragma unroll
    for (int ks = 0; ks < 8; ++ks) {
        short8 a = ld8bf(&ns[(size_t)rid * 256 + ks * 32 + ((l >> 4) << 3)]);
        #pragma unroll
        for (int ci = 0; ci < 2; ++ci) {
            int ct = w * 2 + ci;
            short8 b = *(const short8*)&pf[(((ks * 8 + ct) << 6) + l) * 8];
            acc[ci] = __builtin_amdgcn_mfma_f32_16x16x32_bf16(a, b, acc[ci], 0, 0, 0);
        }
    }
    #pragma unroll
    for (int reg = 0; reg < 4; ++reg) {
        int row16 = start + ((l >> 4) << 2) + reg;
        if (row16 < c) {
            int gid = list[base[e] + row16];
            #pragma unroll
            for (int ci = 0; ci < 2; ++ci)
                center_bf[(size_t)gid * 128 + (w * 2 + ci) * 16 + (l & 15)] = f2bf(acc[ci][reg]);
        }
    }
}

// ---------- final: 3 blocks/CU via halved bucket staging ----------
// Bucket C = P[:,0:16]@X[0:16,:] + P[:,16:32]@X[16:32,:]. Each half stages only
// 16 edges (4 KB/wave) into xs; the K=32 MFMA runs with A zeroed on k>=16
// (lane groups 2,3) so aliased B-reads there contribute 0. Half 1 stages edges
// 16..31 into slots 0..15 (from the pre-saved xp[1]) and sources md1.
// xs layout (16 edges x 128 ch bf16, generic off):
//   off(e,ch) = (ch>>4)*256 + (e>>2)*64 + ((e&3)^(e>>2))*16 + (ch&15),  e in 0..15
// Write: lane owns e=l&15, ch0=ks*32+(l>>4)*8 -> ch>>4 = ks*2+(l>>5) const,
//   ch&15 = ((l>>4)&1)*8 + j contiguous -> one aligned b128 per ks.
// Read: E' = ((l>>4)&1)*8+jj -> groups {0,2},{1,3} read identical addrs
//   (broadcast, free) = 2-way [m136].
// LDS total: qlds 35.1 KB + xs 16.4 KB = 51.5 KB -> 3 blocks/CU (12 waves/CU).
#define QSTRIDE 1096
__global__ __launch_bounds__(256, 3)
void k_final(const unsigned short* __restrict__ center_bf,
             const unsigned short* __restrict__ BallQfrag,
             const unsigned short* __restrict__ RVFfrag,
             const int* __restrict__ adj, const int* __restrict__ rel,
             const float* __restrict__ fcb, float* __restrict__ out) {
    __shared__ unsigned short qlds[16 * QSTRIDE];            // ~35 KB
    __shared__ __align__(16) unsigned short xs[4][2048];     // 16 KB: per-wave 16-edge staging
    int w = threadIdx.x >> 6, l = threadIdx.x & 63;
    int n0 = blockIdx.x * 16;

    // ---- preload adjacency/relations for this wave's 4 nodes (index dep only on l&15)
    int aiq[4][2], rvq[4][2], rvrow[4][2];
    #pragma unroll
    for (int q = 0; q < 4; ++q) {
        int n = n0 + w * 4 + q;
        #pragma unroll
        for (int t = 0; t < 2; ++t) {
            aiq[q][t] = adj[n * DD + t * 16 + (l & 15)];
            rvq[q][t] = rel[n * DD + t * 16 + (l & 15)];
            rvrow[q][t] = aiq[q][t] > 0 ? aiq[q][t] - 1 : 0;
        }
    }

    // X prefetch for q=0 (lands under phase A): xp[t][ks] = X[edge t*16+(l&15)][ks*32+(l>>4)*8..+8]
    short8 xp[2][4];
    #pragma unroll
    for (int t = 0; t < 2; ++t)
        #pragma unroll
        for (int ks = 0; ks < 4; ++ks)
            xp[t][ks] = *(const short8*)&center_bf[(size_t)rvrow[0][t] * 128 + ks * 32 + ((l >> 4) << 3)];

    // phase A: qr tile (16 nodes x 1024) into LDS; wave w computes cols w*256..+256
    {
        short8 a[4];
        #pragma unroll
        for (int ks = 0; ks < 4; ++ks)
            a[ks] = *(const short8*)&center_bf[(size_t)(n0 + (l & 15)) * 128 + ks * 32 + ((l >> 4) << 3)];
        for (int ci = 0; ci < 16; ++ci) {
            int ct = w * 16 + ci;
            float4v acc = {};
            #pragma unroll
            for (int ks = 0; ks < 4; ++ks) {
                short8 b = *(const short8*)&BallQfrag[(((ks * 64 + ct) << 6) + l) * 8];
                acc = __builtin_amdgcn_mfma_f32_16x16x32_bf16(a[ks], b, acc, 0, 0, 0);
            }
            int r = ct >> 3;
            int ch = (ct & 7) * 16 + (l & 15);
            #pragma unroll
            for (int reg = 0; reg < 4; ++reg) {
                int rn = ((l >> 4) << 2) + reg;
                qlds[rn * QSTRIDE + r * 136 + ch] = f2bf(acc[reg]);
            }
        }
    }
    __syncthreads();

    unsigned short* xsw = &xs[w][0];
    int ebase = ((l >> 4) & 1) * 8;          // B-frag edge base within half
    int wbase;                               // write base for lane's staged edge
    {
        int e = l & 15;
        int est = e >> 2;
        int slot = (e & 3) ^ est;
        wbase = est * 64 + slot * 16 + ebase;
    }

    // phase B: wave w handles nodes n0 + w*4 .. +4
    #pragma unroll
    for (int q = 0; q < 4; ++q) {
        int tn = w * 4 + q;
        int ai0 = aiq[q][0], ai1 = aiq[q][1];
        int rv0 = rvq[q][0], rv1 = rvq[q][1];

        // 1. scores^T: S[rel(m, dup x2)][edge n=l&15] = mfma(A=qb, B=xp)
        float4v sc[2] = {};
        #pragma unroll
        for (int ks = 0; ks < 4; ++ks) {
            short8 qb = *(const short8*)&qlds[tn * QSTRIDE + (l & 7) * 136 + ks * 32 + ((l >> 4) << 3)];
            sc[0] = __builtin_amdgcn_mfma_f32_16x16x32_bf16(qb, xp[0][ks], sc[0], 0, 0, 0);
            sc[1] = __builtin_amdgcn_mfma_f32_16x16x32_bf16(qb, xp[1][ks], sc[1], 0, 0, 0);
        }

        // 2. stage half 0 (edges 0..15) from xp[0]; save xp[1] before prefetch clobbers
        #pragma unroll
        for (int ks = 0; ks < 4; ++ks)
            *(short8*)&xsw[(ks * 2 + (l >> 5)) * 256 + wbase] = xp[0][ks];
        short8 xh1[4];
        #pragma unroll
        for (int ks = 0; ks < 4; ++ks) xh1[ks] = xp[1][ks];

        // 3. prefetch next q's X (hides under softmax + bucket half 0)
        if (q < 3) {
            #pragma unroll
            for (int t = 0; t < 2; ++t)
                #pragma unroll
                for (int ks = 0; ks < 4; ++ks)
                    xp[t][ks] = *(const short8*)&center_bf[(size_t)rvrow[q + 1][t] * 128
                                                           + ks * 32 + ((l >> 4) << 3)];
        }

        // 4. select S[rv][own edge]: row rv -> group rv>>2, reg rv&3; source lane
        //    shares l&15 -> same rv -> in-lane reg-select then one shfl.
        float sel0, sel1;
        {
            int r = rv0;
            float v01 = (r & 1) ? sc[0][1] : sc[0][0];
            float v23 = (r & 1) ? sc[0][3] : sc[0][2];
            float regv = (r & 2) ? v23 : v01;
            float s = __shfl(regv, ((r >> 2) << 4) | (l & 15), 64);
            if (ai0 == 0) s = 0.f;
            if (r == 0) s = -1e9f;
            sel0 = fminf(s, 60.f);     // overflow guard for exp (keeps -1e9)
        }
        {
            int r = rv1;
            float v01 = (r & 1) ? sc[1][1] : sc[1][0];
            float v23 = (r & 1) ? sc[1][3] : sc[1][2];
            float regv = (r & 2) ? v23 : v01;
            float s = __shfl(regv, ((r >> 2) << 4) | (l & 15), 64);
            if (ai1 == 0) s = 0.f;
            if (r == 0) s = -1e9f;
            sel1 = fminf(s, 60.f);
        }

        // 5. softmax (no max-shift): exp -> sum tree (2 DPP + 2 shfl) -> normalize
        float at0 = __expf(sel0);
        float at1 = __expf(sel1);
        float sm = at0 + at1;
        sm += dppq<DPP_XOR1>(sm);
        sm += dppq<DPP_XOR2>(sm);
        sm += __shfl_xor(sm, 4, 64);
        sm += __shfl_xor(sm, 8, 64);
        float inv = 1.0f / fmaxf(sm, 1e-30f);
        at0 *= inv; at1 *= inv;
        if (ai0 == 0) at0 = 0.f;          // pad rows contribute 0
        if (ai1 == 0) at1 = 0.f;

        unsigned md0 = (unsigned)f2bf(at0) | ((unsigned)rv0 << 16);
        unsigned md1 = (unsigned)f2bf(at1) | ((unsigned)rv1 << 16);

        float4v bacc[8] = {};

        // 6. bucket half 0: A-frag from md0 (k 0..15 live; k>=16 zero -> aliased B ok)
        {
            unsigned aw[4];
            #pragma unroll
            for (int jp = 0; jp < 4; ++jp) {
                unsigned m0 = __shfl(md0, (l & 48) | (ebase + jp * 2), 64);
                unsigned m1 = __shfl(md0, (l & 48) | (ebase + jp * 2 + 1), 64);
                unsigned s0 = ((m0 >> 16) == (unsigned)(l & 15)) ? (m0 & 0xFFFFu) : 0u;
                unsigned s1 = ((m1 >> 16) == (unsigned)(l & 15)) ? (m1 & 0xFFFFu) : 0u;
                aw[jp] = (l < 32) ? (s0 | (s1 << 16)) : 0u;
            }
            uint4v av = {aw[0], aw[1], aw[2], aw[3]};
            short8 afrag = __builtin_bit_cast(short8, av);
            #pragma unroll
            for (int ct = 0; ct < 8; ++ct) {
                unsigned short p[8];
                #pragma unroll
                for (int jj = 0; jj < 8; ++jj) {
                    int ep = ebase + jj;
                    int st = ep >> 2;
                    int slot = (ep & 3) ^ st;
                    p[jj] = xsw[ct * 256 + st * 64 + slot * 16 + (l & 15)];
                }
                uint4v bv = {(unsigned)p[0] | ((unsigned)p[1] << 16),
                             (unsigned)p[2] | ((unsigned)p[3] << 16),
                             (unsigned)p[4] | ((unsigned)p[5] << 16),
                             (unsigned)p[6] | ((unsigned)p[7] << 16)};
                bacc[ct] = __builtin_amdgcn_mfma_f32_16x16x32_bf16(
                    afrag, __builtin_bit_cast(short8, bv), bacc[ct], 0, 0, 0);
            }
        }

        // 7. stage half 1 (edges 16..31 -> slots 0..15) from saved regs; in-order DS
        //    pipe guarantees prior reads complete first.
        #pragma unroll
        for (int ks = 0; ks < 4; ++ks)
            *(short8*)&xsw[(ks * 2 + (l >> 5)) * 256 + wbase] = xh1[ks];

        // 8. bucket half 1: A-frag from md1 (same k mapping; data aliases to half-1 edges)
        {
            unsigned aw[4];
            #pragma unroll
            for (int jp = 0; jp < 4; ++jp) {
                unsigned m0 = __shfl(md1, (l & 48) | (ebase + jp * 2), 64);
                unsigned m1 = __shfl(md1, (l & 48) | (ebase + jp * 2 + 1), 64);
                unsigned s0 = ((m0 >> 16) == (unsigned)(l & 15)) ? (m0 & 0xFFFFu) : 0u;
                unsigned s1 = ((m1 >> 16) == (unsigned)(l & 15)) ? (m1 & 0xFFFFu) : 0u;
                aw[jp] = (l < 32) ? (s0 | (s1 << 16)) : 0u;
            }
            uint4v av = {aw[0], aw[1], aw[2], aw[3]};
            short8 afrag = __builtin_bit_cast(short8, av);
            #pragma unroll
            for (int ct = 0; ct < 8; ++ct) {
                unsigned short p[8];
                #pragma unroll
                for (int jj = 0; jj < 8; ++jj) {
                    int ep = ebase + jj;
                    int st = ep >> 2;
                    int slot = (ep & 3) ^ st;
                    p[jj] = xsw[ct * 256 + st * 64 + slot * 16 + (l & 15)];
                }
                uint4v bv = {(unsigned)p[0] | ((unsigned)p[1] << 16),
                             (unsigned)p[2] | ((unsigned)p[3] << 16),
                             (unsigned)p[4] | ((unsigned)p[5] << 16),
                             (unsigned)p[6] | ((unsigned)p[7] << 16)};
                bacc[ct] = __builtin_amdgcn_mfma_f32_16x16x32_bf16(
                    afrag, __builtin_bit_cast(short8, bv), bacc[ct], 0, 0, 0);
            }
        }

        // 9. store bucket rows (C rows 0..7 = relations; rows 8..15 are zero)
        if (l < 32) {
            int rbase = (l >> 4) << 2;
            #pragma unroll
            for (int ct = 0; ct < 8; ++ct)
                #pragma unroll
                for (int reg = 0; reg < 4; ++reg)
                    qlds[tn * QSTRIDE + (rbase + reg) * 136 + ct * 16 + (l & 15)] = f2bf(bacc[ct][reg]);
        }
    }
    __syncthreads();

    // phase C: agg16x128 = bucket(16x1024, r-stride 136) @ RVF(1024x128), fused epilogue
    // A-operand hoisted: one ds_read per ks feeds both ci accumulators.
    {
        float4v acc[2] = {};
        #pragma unroll 4
        for (int ks = 0; ks < 32; ++ks) {
            short8 a = *(const short8*)&qlds[(l & 15) * QSTRIDE + (ks >> 2) * 136
                                             + (ks & 3) * 32 + ((l >> 4) << 3)];
            #pragma unroll
            for (int ci = 0; ci < 2; ++ci) {
                int ct = w * 2 + ci;
                short8 b = *(const short8*)&RVFfrag[(((ks * 8 + ct) << 6) + l) * 8];
                acc[ci] = __builtin_amdgcn_mfma_f32_16x16x32_bf16(a, b, acc[ci], 0, 0, 0);
            }
        }
        #pragma unroll
        for (int ci = 0; ci < 2; ++ci) {
            int ct = w * 2 + ci;
            int col = ct * 16 + (l & 15);
            float bb = fcb[col];
            #pragma unroll
            for (int reg = 0; reg < 4; ++reg) {
                int n = n0 + ((l >> 4) << 2) + reg;
                float v = acc[ci][reg] + bb;
                v = v > 0.f ? v : 0.f;
                out[(size_t)n * 128 + col] = bf2f(center_bf[(size_t)n * 128 + col]) + v;
            }
        }
    }
}

extern "C" void kernel_launch(void* const* d_in, const int* in_sizes, int n_in,
                              void* d_out, int out_size, void* d_ws, size_t ws_size,
                              hipStream_t stream) {
    const float* node_state = (const float*)d_in[0];
    const int*   adjacency  = (const int*)d_in[1];
    const int*   point_enc  = (const int*)d_in[2];
    const int*   relation   = (const int*)d_in[3];
    const float* pew        = (const float*)d_in[4];
    const float* relw       = (const float*)d_in[5];
    const float* qw         = (const float*)d_in[6];
    const float* kw         = (const float*)d_in[7];
    const float* vw         = (const float*)d_in[8];
    const float* fcw        = (const float*)d_in[9];
    const float* fcb        = (const float*)d_in[10];
    float* out = (float*)d_out;

    char* ws = (char*)d_ws;
    unsigned short* BallQfrag = (unsigned short*)ws;  ws += 128 * 1024 * 2;            // 256 KB
    unsigned short* RVFfrag   = (unsigned short*)ws;  ws += 1024 * 128 * 2;            // 256 KB
    unsigned short* center_bf = (unsigned short*)ws;  ws += (size_t)NNODE * 128 * 2;   // 4 MB
    unsigned short* pewfrag   = (unsigned short*)ws;  ws += 8 * 32768 * 2;             // 512 KB
    int* blockhist            = (int*)ws;             ws += 64 * 8 * 4;
    int* cnt                  = (int*)ws;             ws += 32;
    int* basep                = (int*)ws;             ws += 32;
    int* list                 = (int*)ws;             ws += NNODE * 4;                 // 64 KB

    k_setup<<<1152, 256, 0, stream>>>(pew, qw, kw, relw, vw, fcw, point_enc,
                                      pewfrag, BallQfrag, RVFfrag, blockhist);
    k_scatter<<<64, 256, 0, stream>>>(point_enc, blockhist, list, cnt, basep);
    k_center<<<dim3(192, 8), 256, 0, stream>>>(node_state, pewfrag, list, cnt, basep, center_bf);
    k_final<<<NNODE / 16, 256, 0, stream>>>(center_bf, BallQfrag, RVFfrag,
                                            adjacency, relation, fcb, out);
}